// Round 1
// baseline (176.807 us; speedup 1.0000x reference)
//
#include <hip/hip_runtime.h>

#define HL 32
#define WL 32
#define HH 512
#define WH 512
#define NB 12
#define NC 128
#define C2 129      // 128 numerator channels + 1 denominator
#define CPAD 132    // global grid cell stride (floats), 16B aligned
#define TH 16       // slice tile height
#define TW 32       // slice tile width
#define NCELL (NB*3*4)   // 12 z * 3 rows * 4 cols = 144

// ---------------- kernel A: luma_hr = mean over 3 guide channels ----------
__global__ void k_luma(const float* __restrict__ guide, float* __restrict__ luma) {
  int i = blockIdx.x * 256 + threadIdx.x;
  if (i >= 2 * HH * WH) return;
  int b = i >> 18;            // HH*WH = 262144 = 1<<18
  int p = i & ((1 << 18) - 1);
  const float* g = guide + ((size_t)b * 3 << 18) + p;
  luma[i] = (g[0] + g[1 << 18] + g[2 << 18]) / 3.0f;
}

// ---------------- kernel B: jax.image.resize bilinear+antialias 512 -> 32 --
// scale = 1/16, kernel_scale = 16, sample_f = 16*o + 7.5, taps j in [16o-8, 16o+23]
// weight = 1 - |j - sample_f|/16, normalized per-axis over VALID taps only.
__global__ void k_down(const float* __restrict__ luma_hr, float* __restrict__ luma_lr) {
  int i = blockIdx.x * 256 + threadIdx.x;
  if (i >= 2 * HL * WL) return;
  int b = i >> 10;
  int r = i & 1023;
  int oy = r >> 5, ox = r & 31;
  float posy = 16.f * oy + 7.5f;
  float posx = 16.f * ox + 7.5f;
  int jx0 = 16 * ox - 8;
  int jy0 = 16 * oy - 8;
  float wx[32];
  float sumx = 0.f;
#pragma unroll
  for (int s = 0; s < 32; ++s) {
    int j = jx0 + s;
    float w = 0.f;
    if (j >= 0 && j < WH) { w = 1.f - fabsf((float)j - posx) * (1.f / 16.f); sumx += w; }
    wx[s] = w;
  }
  float sumy = 0.f, acc = 0.f;
  const float* src = luma_hr + ((size_t)b << 18);
#pragma unroll 1
  for (int t = 0; t < 32; ++t) {
    int jy = jy0 + t;
    if (jy < 0 || jy >= HH) continue;
    float wy = 1.f - fabsf((float)jy - posy) * (1.f / 16.f);
    sumy += wy;
    const float* row = src + (size_t)jy * WH;
    float rowacc = 0.f;
#pragma unroll
    for (int s = 0; s < 32; ++s) {
      int jx = jx0 + s;
      if (jx >= 0 && jx < WH) rowacc += wx[s] * row[jx];
    }
    acc += wy * rowacc;
  }
  luma_lr[i] = acc / (sumy * sumx);
}

// ---------------- kernel C: build box-filtered bilateral grid -------------
// G[b][z][y][x][c] c-contiguous with stride CPAD; c in [0,127] = feat*w, c=128 = w
__global__ void k_grid(const float* __restrict__ feat, const float* __restrict__ luma_lr,
                       const float* __restrict__ sx_raw, const float* __restrict__ sy_raw,
                       const float* __restrict__ sr_raw, float* __restrict__ grid) {
  int bid = blockIdx.x;                 // b*1024 + y*32 + x
  int b = bid >> 10;
  int yx = bid & 1023;
  int y = yx >> 5, x = yx & 31;
  __shared__ float wsm[NB * 9];
  int t = threadIdx.x;                  // 128 threads
  if (t < NB * 9) {
    int k = t / 9;
    int j = t - k * 9;
    int dy = j / 3 - 1, dx = (j % 3) - 1;
    int yy = y + dy, xx = x + dx;
    float wv = 0.f;
    if (yy >= 0 && yy < HL && xx >= 0 && xx < WL) {
      int p = yy * WL + xx;
      float lum = luma_lr[b * (HL * WL) + p];
      float dn = expf(sr_raw[p]) * 12.0f + 1e-5f;
      float d = fabsf(lum * 11.0f - (float)k);
      wv = fmaxf(1.0f - d / dn, 0.0f);
    }
    wsm[t] = wv;
  }
  __syncthreads();
  int p0 = y * WL + x;
  float scale = (1.0f + 0.01f * (expf(sx_raw[p0]) + expf(sy_raw[p0]))) * (1.0f / 9.0f);
  float f[9];
  const float* fb = feat + ((size_t)(b * NC) + t) * (HL * WL);
#pragma unroll
  for (int j = 0; j < 9; ++j) {
    int dy = j / 3 - 1, dx = (j % 3) - 1;
    int yy = y + dy, xx = x + dx;
    f[j] = (yy >= 0 && yy < HL && xx >= 0 && xx < WL) ? fb[yy * WL + xx] : 0.f;
  }
#pragma unroll 1
  for (int z = 0; z < NB; ++z) {
    float acc = 0.f;
#pragma unroll
    for (int j = 0; j < 9; ++j) acc += f[j] * wsm[z * 9 + j];
    grid[(((size_t)(b * NB + z) * HL + y) * WL + x) * CPAD + t] = acc * scale;
  }
  if (t < NB) {
    float s = 0.f;
#pragma unroll
    for (int j = 0; j < 9; ++j) s += wsm[t * 9 + j];
    grid[(((size_t)(b * NB + t) * HL + y) * WL + x) * CPAD + NC] = s * scale;
  }
}

// ---------------- kernel D: slice (trilinear sample + divide) -------------
__global__ __launch_bounds__(512) void k_slice(const float* __restrict__ grid,
                                               const float* __restrict__ luma_hr,
                                               float* __restrict__ out) {
  __shared__ float lds[NCELL * C2];     // 144 cells * 129 floats = 74304 B
  int bid = blockIdx.x;                 // 1024 blocks: b(2) x th(32) x tw(16)
  int b = bid >> 9;
  int t = bid & 511;
  int th = t >> 4, tw = t & 15;
  int h0 = th * TH, w0 = tw * TW;
  const float SCC = 31.0f / 511.0f;
  int fy = (int)((float)h0 * SCC);
  int fx = (int)((float)w0 * SCC);
  int tid = threadIdx.x;
  // --- stage footprint: 12 z * 3 rows * 4 cols, channels contiguous ---
  {
    int g = tid >> 5, lane = tid & 31;
    for (int cell = g; cell < NCELL; cell += 16) {
      int z = cell / 12;
      int rr = cell - z * 12;
      int ry = rr >> 2, rx = rr & 3;
      int gy = min(fy + ry, HL - 1);
      int gx = min(fx + rx, WL - 1);
      const float* src = grid + (((size_t)(b * NB + z) * HL + gy) * WL + gx) * CPAD;
      float* dst = lds + cell * C2;
      for (int c = lane; c < C2; c += 32) dst[c] = src[c];
    }
  }
  __syncthreads();
  // --- per-pixel trilinear ---
  int lw = tid & 31, lh = tid >> 5;
  int h = h0 + lh, w = w0 + lw;
  float luma = luma_hr[((size_t)b << 18) + h * WH + w];
  float wz = fminf(fmaxf(luma * 11.0f, 0.0f), 11.0f);
  float u = fminf((float)w * SCC, 31.0f);
  float v = fminf((float)h * SCC, 31.0f);
  int x0 = (int)u; float fxw = u - (float)x0; int x1 = min(x0 + 1, WL - 1);
  int y0 = (int)v; float fyw = v - (float)y0; int y1 = min(y0 + 1, HL - 1);
  int z0 = (int)wz; float fzw = wz - (float)z0; int z1 = min(z0 + 1, NB - 1);
  int rx0 = min(max(x0 - fx, 0), 3), rx1 = min(max(x1 - fx, 0), 3);
  int ry0 = min(max(y0 - fy, 0), 2), ry1 = min(max(y1 - fy, 0), 2);
  int b000 = ((z0 * 3 + ry0) * 4 + rx0) * C2;
  int b001 = ((z0 * 3 + ry0) * 4 + rx1) * C2;
  int b010 = ((z0 * 3 + ry1) * 4 + rx0) * C2;
  int b011 = ((z0 * 3 + ry1) * 4 + rx1) * C2;
  int b100 = ((z1 * 3 + ry0) * 4 + rx0) * C2;
  int b101 = ((z1 * 3 + ry0) * 4 + rx1) * C2;
  int b110 = ((z1 * 3 + ry1) * 4 + rx0) * C2;
  int b111 = ((z1 * 3 + ry1) * 4 + rx1) * C2;
  float z0w = 1.f - fzw, z1w = fzw;
  float y0w = 1.f - fyw, y1w = fyw;
  float x0w = 1.f - fxw, x1w = fxw;
  float w000 = z0w * y0w * x0w, w001 = z0w * y0w * x1w;
  float w010 = z0w * y1w * x0w, w011 = z0w * y1w * x1w;
  float w100 = z1w * y0w * x0w, w101 = z1w * y0w * x1w;
  float w110 = z1w * y1w * x0w, w111 = z1w * y1w * x1w;
  float den = w000 * lds[b000 + NC] + w001 * lds[b001 + NC] +
              w010 * lds[b010 + NC] + w011 * lds[b011 + NC] +
              w100 * lds[b100 + NC] + w101 * lds[b101 + NC] +
              w110 * lds[b110 + NC] + w111 * lds[b111 + NC];
  float rinv = 1.0f / fmaxf(den, 1e-8f);
  float* op = out + ((size_t)(b * NC) << 18) + (size_t)h * WH + w;
#pragma unroll 4
  for (int c = 0; c < NC; ++c) {
    float num = w000 * lds[b000 + c] + w001 * lds[b001 + c] +
                w010 * lds[b010 + c] + w011 * lds[b011 + c] +
                w100 * lds[b100 + c] + w101 * lds[b101 + c] +
                w110 * lds[b110 + c] + w111 * lds[b111 + c];
    __builtin_nontemporal_store(num * rinv, op + ((size_t)c << 18));
  }
}

extern "C" void kernel_launch(void* const* d_in, const int* in_sizes, int n_in,
                              void* d_out, int out_size, void* d_ws, size_t ws_size,
                              hipStream_t stream) {
  const float* feat   = (const float*)d_in[0];  // (2,128,32,32)
  const float* guide  = (const float*)d_in[1];  // (2,3,512,512)
  const float* sx_raw = (const float*)d_in[2];  // (1,1,32,32)
  const float* sy_raw = (const float*)d_in[3];  // (1,1,32,32)
  // d_in[4] = th_raw: computed in reference but unused by the output
  const float* sr_raw = (const float*)d_in[5];  // (1,1,32,32)
  float* out = (float*)d_out;

  char* ws = (char*)d_ws;
  float* luma_hr = (float*)ws;                                  // 524288 floats (2 MB)
  float* luma_lr = (float*)(ws + (size_t)524288 * 4);           // 2048 floats
  float* grid    = (float*)(ws + (size_t)524288 * 4 + 2048 * 4);// 3244032 floats (~12.4 MB)

  k_luma<<<2048, 256, 0, stream>>>(guide, luma_hr);
  k_down<<<8, 256, 0, stream>>>(luma_hr, luma_lr);
  k_grid<<<2048, 128, 0, stream>>>(feat, luma_lr, sx_raw, sy_raw, sr_raw, grid);
  k_slice<<<1024, 512, 0, stream>>>(grid, luma_hr, out);
}

// Round 2
// 157.561 us; speedup vs baseline: 1.1221x; 1.1221x over previous
//
#include <hip/hip_runtime.h>

#define HL 32
#define WL 32
#define HH 512
#define WH 512
#define NB 12
#define NC 128
#define C2 129      // 128 numerator channels + 1 denominator
#define CPAD 132    // cell stride in floats (global AND lds), 16B aligned
#define TH 16       // slice tile height
#define TW 32       // slice tile width
#define NCELL (NB*3*4)   // 12 z * 3 rows * 4 cols = 144

// ---------------- kernel A: luma_hr = mean over 3 guide channels ----------
__global__ void k_luma(const float* __restrict__ guide, float* __restrict__ luma) {
  int i = blockIdx.x * 256 + threadIdx.x;
  if (i >= 2 * HH * WH) return;
  int b = i >> 18;
  int p = i & ((1 << 18) - 1);
  const float* g = guide + ((size_t)b * 3 << 18) + p;
  luma[i] = (g[0] + g[1 << 18] + g[2 << 18]) / 3.0f;
}

// ---------------- kernel B: jax.image.resize bilinear+antialias 512 -> 32 --
__global__ void k_down(const float* __restrict__ luma_hr, float* __restrict__ luma_lr) {
  int i = blockIdx.x * 256 + threadIdx.x;
  if (i >= 2 * HL * WL) return;
  int b = i >> 10;
  int r = i & 1023;
  int oy = r >> 5, ox = r & 31;
  float posy = 16.f * oy + 7.5f;
  float posx = 16.f * ox + 7.5f;
  int jx0 = 16 * ox - 8;
  int jy0 = 16 * oy - 8;
  float wx[32];
  float sumx = 0.f;
#pragma unroll
  for (int s = 0; s < 32; ++s) {
    int j = jx0 + s;
    float w = 0.f;
    if (j >= 0 && j < WH) { w = 1.f - fabsf((float)j - posx) * (1.f / 16.f); sumx += w; }
    wx[s] = w;
  }
  float sumy = 0.f, acc = 0.f;
  const float* src = luma_hr + ((size_t)b << 18);
#pragma unroll 1
  for (int t = 0; t < 32; ++t) {
    int jy = jy0 + t;
    if (jy < 0 || jy >= HH) continue;
    float wy = 1.f - fabsf((float)jy - posy) * (1.f / 16.f);
    sumy += wy;
    const float* row = src + (size_t)jy * WH;
    float rowacc = 0.f;
#pragma unroll
    for (int s = 0; s < 32; ++s) {
      int jx = jx0 + s;
      if (jx >= 0 && jx < WH) rowacc += wx[s] * row[jx];
    }
    acc += wy * rowacc;
  }
  luma_lr[i] = acc / (sumy * sumx);
}

// ---------------- kernel C: build box-filtered bilateral grid -------------
__global__ void k_grid(const float* __restrict__ feat, const float* __restrict__ luma_lr,
                       const float* __restrict__ sx_raw, const float* __restrict__ sy_raw,
                       const float* __restrict__ sr_raw, float* __restrict__ grid) {
  int bid = blockIdx.x;                 // b*1024 + y*32 + x
  int b = bid >> 10;
  int yx = bid & 1023;
  int y = yx >> 5, x = yx & 31;
  __shared__ float wsm[NB * 9];
  int t = threadIdx.x;                  // 128 threads
  if (t < NB * 9) {
    int k = t / 9;
    int j = t - k * 9;
    int dy = j / 3 - 1, dx = (j % 3) - 1;
    int yy = y + dy, xx = x + dx;
    float wv = 0.f;
    if (yy >= 0 && yy < HL && xx >= 0 && xx < WL) {
      int p = yy * WL + xx;
      float lum = luma_lr[b * (HL * WL) + p];
      float dn = expf(sr_raw[p]) * 12.0f + 1e-5f;
      float d = fabsf(lum * 11.0f - (float)k);
      wv = fmaxf(1.0f - d / dn, 0.0f);
    }
    wsm[t] = wv;
  }
  __syncthreads();
  int p0 = y * WL + x;
  float scale = (1.0f + 0.01f * (expf(sx_raw[p0]) + expf(sy_raw[p0]))) * (1.0f / 9.0f);
  float f[9];
  const float* fb = feat + ((size_t)(b * NC) + t) * (HL * WL);
#pragma unroll
  for (int j = 0; j < 9; ++j) {
    int dy = j / 3 - 1, dx = (j % 3) - 1;
    int yy = y + dy, xx = x + dx;
    f[j] = (yy >= 0 && yy < HL && xx >= 0 && xx < WL) ? fb[yy * WL + xx] : 0.f;
  }
#pragma unroll 1
  for (int z = 0; z < NB; ++z) {
    float acc = 0.f;
#pragma unroll
    for (int j = 0; j < 9; ++j) acc += f[j] * wsm[z * 9 + j];
    grid[(((size_t)(b * NB + z) * HL + y) * WL + x) * CPAD + t] = acc * scale;
  }
  if (t < NB) {
    float s = 0.f;
#pragma unroll
    for (int j = 0; j < 9; ++j) s += wsm[t * 9 + j];
    grid[(((size_t)(b * NB + t) * HL + y) * WL + x) * CPAD + NC] = s * scale;
  }
}

// ---------------- kernel D: slice (trilinear sample + divide) -------------
__global__ __launch_bounds__(512) void k_slice(const float* __restrict__ grid,
                                               const float* __restrict__ luma_hr,
                                               float* __restrict__ out) {
  __shared__ __align__(16) float lds[NCELL * CPAD];   // 144*132*4 = 76032 B
  int bid = blockIdx.x;                 // 1024 blocks: b(2) x th(32) x tw(16)
  int b = bid >> 9;
  int t = bid & 511;
  int th = t >> 4, tw = t & 15;
  int h0 = th * TH, w0 = tw * TW;
  const float SCC = 31.0f / 511.0f;
  int fy = (int)((float)h0 * SCC);
  int fx = (int)((float)w0 * SCC);
  int tid = threadIdx.x;
  // --- stage footprint as float4 (CPAD=132 floats = 33 float4 per cell) ---
  {
    const float4* __restrict__ g4 = (const float4*)grid;
    float4* l4 = (float4*)lds;
    for (int i = tid; i < NCELL * 33; i += 512) {
      int cell = i / 33;
      int q = i - cell * 33;
      int z = cell / 12;
      int rr = cell - z * 12;
      int ry = rr >> 2, rx = rr & 3;
      int gy = min(fy + ry, HL - 1);
      int gx = min(fx + rx, WL - 1);
      size_t src = (((size_t)(b * NB + z) * HL + gy) * WL + gx) * 33 + q;
      l4[i] = g4[src];
    }
  }
  __syncthreads();
  // --- per-pixel trilinear ---
  int lw = tid & 31, lh = tid >> 5;
  int h = h0 + lh, w = w0 + lw;
  float luma = luma_hr[((size_t)b << 18) + h * WH + w];
  float wz = fminf(fmaxf(luma * 11.0f, 0.0f), 11.0f);
  float u = fminf((float)w * SCC, 31.0f);
  float v = fminf((float)h * SCC, 31.0f);
  int x0 = (int)u; float fxw = u - (float)x0; int x1 = min(x0 + 1, WL - 1);
  int y0 = (int)v; float fyw = v - (float)y0; int y1 = min(y0 + 1, HL - 1);
  int z0 = (int)wz; float fzw = wz - (float)z0; int z1 = min(z0 + 1, NB - 1);
  int rx0 = min(max(x0 - fx, 0), 3), rx1 = min(max(x1 - fx, 0), 3);
  int ry0 = min(max(y0 - fy, 0), 2), ry1 = min(max(y1 - fy, 0), 2);
  // float4-unit cell bases (cell * 33)
  int o000 = ((z0 * 3 + ry0) * 4 + rx0) * 33;
  int o001 = ((z0 * 3 + ry0) * 4 + rx1) * 33;
  int o010 = ((z0 * 3 + ry1) * 4 + rx0) * 33;
  int o011 = ((z0 * 3 + ry1) * 4 + rx1) * 33;
  int o100 = ((z1 * 3 + ry0) * 4 + rx0) * 33;
  int o101 = ((z1 * 3 + ry0) * 4 + rx1) * 33;
  int o110 = ((z1 * 3 + ry1) * 4 + rx0) * 33;
  int o111 = ((z1 * 3 + ry1) * 4 + rx1) * 33;
  float z0w = 1.f - fzw, z1w = fzw;
  float y0w = 1.f - fyw, y1w = fyw;
  float x0w = 1.f - fxw, x1w = fxw;
  float w000 = z0w * y0w * x0w, w001 = z0w * y0w * x1w;
  float w010 = z0w * y1w * x0w, w011 = z0w * y1w * x1w;
  float w100 = z1w * y0w * x0w, w101 = z1w * y0w * x1w;
  float w110 = z1w * y1w * x0w, w111 = z1w * y1w * x1w;
  float den = w000 * lds[o000 * 4 + NC] + w001 * lds[o001 * 4 + NC] +
              w010 * lds[o010 * 4 + NC] + w011 * lds[o011 * 4 + NC] +
              w100 * lds[o100 * 4 + NC] + w101 * lds[o101 * 4 + NC] +
              w110 * lds[o110 * 4 + NC] + w111 * lds[o111 * 4 + NC];
  float rinv = 1.0f / fmaxf(den, 1e-8f);
  const float4* L = (const float4*)lds;
  float* op = out + ((size_t)(b * NC) << 18) + (size_t)h * WH + w;
#pragma unroll 2
  for (int g = 0; g < 32; ++g) {
    float4 a0 = L[o000 + g], a1 = L[o001 + g], a2 = L[o010 + g], a3 = L[o011 + g];
    float4 a4 = L[o100 + g], a5 = L[o101 + g], a6 = L[o110 + g], a7 = L[o111 + g];
    float vx = w000 * a0.x + w001 * a1.x + w010 * a2.x + w011 * a3.x +
               w100 * a4.x + w101 * a5.x + w110 * a6.x + w111 * a7.x;
    float vy = w000 * a0.y + w001 * a1.y + w010 * a2.y + w011 * a3.y +
               w100 * a4.y + w101 * a5.y + w110 * a6.y + w111 * a7.y;
    float vz = w000 * a0.z + w001 * a1.z + w010 * a2.z + w011 * a3.z +
               w100 * a4.z + w101 * a5.z + w110 * a6.z + w111 * a7.z;
    float vw = w000 * a0.w + w001 * a1.w + w010 * a2.w + w011 * a3.w +
               w100 * a4.w + w101 * a5.w + w110 * a6.w + w111 * a7.w;
    float* o0 = op + ((size_t)(4 * g) << 18);
    __builtin_nontemporal_store(vx * rinv, o0);
    __builtin_nontemporal_store(vy * rinv, o0 + ((size_t)1 << 18));
    __builtin_nontemporal_store(vz * rinv, o0 + ((size_t)2 << 18));
    __builtin_nontemporal_store(vw * rinv, o0 + ((size_t)3 << 18));
  }
}

extern "C" void kernel_launch(void* const* d_in, const int* in_sizes, int n_in,
                              void* d_out, int out_size, void* d_ws, size_t ws_size,
                              hipStream_t stream) {
  const float* feat   = (const float*)d_in[0];  // (2,128,32,32)
  const float* guide  = (const float*)d_in[1];  // (2,3,512,512)
  const float* sx_raw = (const float*)d_in[2];  // (1,1,32,32)
  const float* sy_raw = (const float*)d_in[3];  // (1,1,32,32)
  // d_in[4] = th_raw: unused by the output
  const float* sr_raw = (const float*)d_in[5];  // (1,1,32,32)
  float* out = (float*)d_out;

  char* ws = (char*)d_ws;
  float* luma_hr = (float*)ws;                                  // 524288 floats (2 MB)
  float* luma_lr = (float*)(ws + (size_t)524288 * 4);           // 2048 floats
  float* grid    = (float*)(ws + (size_t)524288 * 4 + 2048 * 4);// 2*12*32*32*132 floats (~13 MB)

  k_luma<<<2048, 256, 0, stream>>>(guide, luma_hr);
  k_down<<<8, 256, 0, stream>>>(luma_hr, luma_lr);
  k_grid<<<2048, 128, 0, stream>>>(feat, luma_lr, sx_raw, sy_raw, sr_raw, grid);
  k_slice<<<1024, 512, 0, stream>>>(grid, luma_hr, out);
}

// Round 3
// 156.610 us; speedup vs baseline: 1.1290x; 1.0061x over previous
//
#include <hip/hip_runtime.h>

#define HL 32
#define WL 32
#define HH 512
#define WH 512
#define NB 12
#define NC 128
#define C2 129      // 128 numerator channels + 1 denominator
#define CPAD 132    // cell stride in floats (global AND lds), 16B aligned
#define TH 16       // slice tile height
#define TW 32       // slice tile width
#define NCELL (NB*3*4)   // 12 z * 3 rows * 4 cols = 144

// ---------------- kernel A: luma_hr = mean over 3 guide channels ----------
__global__ void k_luma(const float* __restrict__ guide, float* __restrict__ luma) {
  int i = blockIdx.x * 256 + threadIdx.x;
  if (i >= 2 * HH * WH) return;
  int b = i >> 18;
  int p = i & ((1 << 18) - 1);
  const float* g = guide + ((size_t)b * 3 << 18) + p;
  luma[i] = (g[0] + g[1 << 18] + g[2 << 18]) / 3.0f;
}

// ---------------- kernel B: jax.image.resize bilinear+antialias 512 -> 32 --
__global__ void k_down(const float* __restrict__ luma_hr, float* __restrict__ luma_lr) {
  int i = blockIdx.x * 256 + threadIdx.x;
  if (i >= 2 * HL * WL) return;
  int b = i >> 10;
  int r = i & 1023;
  int oy = r >> 5, ox = r & 31;
  float posy = 16.f * oy + 7.5f;
  float posx = 16.f * ox + 7.5f;
  int jx0 = 16 * ox - 8;
  int jy0 = 16 * oy - 8;
  float wx[32];
  float sumx = 0.f;
#pragma unroll
  for (int s = 0; s < 32; ++s) {
    int j = jx0 + s;
    float w = 0.f;
    if (j >= 0 && j < WH) { w = 1.f - fabsf((float)j - posx) * (1.f / 16.f); sumx += w; }
    wx[s] = w;
  }
  float sumy = 0.f, acc = 0.f;
  const float* src = luma_hr + ((size_t)b << 18);
#pragma unroll 1
  for (int t = 0; t < 32; ++t) {
    int jy = jy0 + t;
    if (jy < 0 || jy >= HH) continue;
    float wy = 1.f - fabsf((float)jy - posy) * (1.f / 16.f);
    sumy += wy;
    const float* row = src + (size_t)jy * WH;
    float rowacc = 0.f;
#pragma unroll
    for (int s = 0; s < 32; ++s) {
      int jx = jx0 + s;
      if (jx >= 0 && jx < WH) rowacc += wx[s] * row[jx];
    }
    acc += wy * rowacc;
  }
  luma_lr[i] = acc / (sumy * sumx);
}

// ---------------- kernel C: build box-filtered bilateral grid -------------
__global__ void k_grid(const float* __restrict__ feat, const float* __restrict__ luma_lr,
                       const float* __restrict__ sx_raw, const float* __restrict__ sy_raw,
                       const float* __restrict__ sr_raw, float* __restrict__ grid) {
  int bid = blockIdx.x;                 // b*1024 + y*32 + x
  int b = bid >> 10;
  int yx = bid & 1023;
  int y = yx >> 5, x = yx & 31;
  __shared__ float wsm[NB * 9];
  int t = threadIdx.x;                  // 128 threads
  if (t < NB * 9) {
    int k = t / 9;
    int j = t - k * 9;
    int dy = j / 3 - 1, dx = (j % 3) - 1;
    int yy = y + dy, xx = x + dx;
    float wv = 0.f;
    if (yy >= 0 && yy < HL && xx >= 0 && xx < WL) {
      int p = yy * WL + xx;
      float lum = luma_lr[b * (HL * WL) + p];
      float dn = expf(sr_raw[p]) * 12.0f + 1e-5f;
      float d = fabsf(lum * 11.0f - (float)k);
      wv = fmaxf(1.0f - d / dn, 0.0f);
    }
    wsm[t] = wv;
  }
  __syncthreads();
  int p0 = y * WL + x;
  float scale = (1.0f + 0.01f * (expf(sx_raw[p0]) + expf(sy_raw[p0]))) * (1.0f / 9.0f);
  float f[9];
  const float* fb = feat + ((size_t)(b * NC) + t) * (HL * WL);
#pragma unroll
  for (int j = 0; j < 9; ++j) {
    int dy = j / 3 - 1, dx = (j % 3) - 1;
    int yy = y + dy, xx = x + dx;
    f[j] = (yy >= 0 && yy < HL && xx >= 0 && xx < WL) ? fb[yy * WL + xx] : 0.f;
  }
#pragma unroll 1
  for (int z = 0; z < NB; ++z) {
    float acc = 0.f;
#pragma unroll
    for (int j = 0; j < 9; ++j) acc += f[j] * wsm[z * 9 + j];
    grid[(((size_t)(b * NB + z) * HL + y) * WL + x) * CPAD + t] = acc * scale;
  }
  if (t < NB) {
    float s = 0.f;
#pragma unroll
    for (int j = 0; j < 9; ++j) s += wsm[t * 9 + j];
    grid[(((size_t)(b * NB + t) * HL + y) * WL + x) * CPAD + NC] = s * scale;
  }
}

// ---------------- kernel D: slice (trilinear sample + divide) -------------
// LDS cell index: cellL = (ry*4+rx)*12 + z  (z INNERMOST) so that within one
// corner-read instruction (z varies per lane) banks spread as 4*z mod 32
// over 8 bank groups instead of 2. Cell stride stays 33 float4 (132 dwords).
__global__ __launch_bounds__(512) void k_slice(const float* __restrict__ grid,
                                               const float* __restrict__ luma_hr,
                                               float* __restrict__ out) {
  __shared__ __align__(16) float lds[NCELL * CPAD];   // 144*132*4 = 76032 B
  int bid = blockIdx.x;                 // 1024 blocks: b(2) x th(32) x tw(16)
  int b = bid >> 9;
  int t = bid & 511;
  int th = t >> 4, tw = t & 15;
  int h0 = th * TH, w0 = tw * TW;
  const float SCC = 31.0f / 511.0f;
  int fy = (int)((float)h0 * SCC);
  int fx = (int)((float)w0 * SCC);
  int tid = threadIdx.x;
  // --- stage footprint as float4; LDS layout uses cellL (z innermost) ---
  {
    const float4* __restrict__ g4 = (const float4*)grid;
    float4* l4 = (float4*)lds;
    for (int i = tid; i < NCELL * 33; i += 512) {
      int cellL = i / 33;
      int q = i - cellL * 33;
      int rr = cellL / 12;              // ry*4+rx
      int z = cellL - rr * 12;
      int ry = rr >> 2, rx = rr & 3;
      int gy = min(fy + ry, HL - 1);
      int gx = min(fx + rx, WL - 1);
      size_t src = (((size_t)(b * NB + z) * HL + gy) * WL + gx) * 33 + q;
      l4[i] = g4[src];
    }
  }
  __syncthreads();
  // --- per-pixel trilinear ---
  int lw = tid & 31, lh = tid >> 5;
  int h = h0 + lh, w = w0 + lw;
  float luma = luma_hr[((size_t)b << 18) + h * WH + w];
  float wz = fminf(fmaxf(luma * 11.0f, 0.0f), 11.0f);
  float u = fminf((float)w * SCC, 31.0f);
  float v = fminf((float)h * SCC, 31.0f);
  int x0 = (int)u; float fxw = u - (float)x0; int x1 = min(x0 + 1, WL - 1);
  int y0 = (int)v; float fyw = v - (float)y0; int y1 = min(y0 + 1, HL - 1);
  int z0 = (int)wz; float fzw = wz - (float)z0; int z1 = min(z0 + 1, NB - 1);
  int rx0 = min(max(x0 - fx, 0), 3), rx1 = min(max(x1 - fx, 0), 3);
  int ry0 = min(max(y0 - fy, 0), 2), ry1 = min(max(y1 - fy, 0), 2);
  // float4-unit cell bases: ((rr)*12 + z) * 33
  int o000 = ((ry0 * 4 + rx0) * 12 + z0) * 33;
  int o001 = ((ry0 * 4 + rx1) * 12 + z0) * 33;
  int o010 = ((ry1 * 4 + rx0) * 12 + z0) * 33;
  int o011 = ((ry1 * 4 + rx1) * 12 + z0) * 33;
  int o100 = ((ry0 * 4 + rx0) * 12 + z1) * 33;
  int o101 = ((ry0 * 4 + rx1) * 12 + z1) * 33;
  int o110 = ((ry1 * 4 + rx0) * 12 + z1) * 33;
  int o111 = ((ry1 * 4 + rx1) * 12 + z1) * 33;
  float z0w = 1.f - fzw, z1w = fzw;
  float y0w = 1.f - fyw, y1w = fyw;
  float x0w = 1.f - fxw, x1w = fxw;
  float w000 = z0w * y0w * x0w, w001 = z0w * y0w * x1w;
  float w010 = z0w * y1w * x0w, w011 = z0w * y1w * x1w;
  float w100 = z1w * y0w * x0w, w101 = z1w * y0w * x1w;
  float w110 = z1w * y1w * x0w, w111 = z1w * y1w * x1w;
  float den = w000 * lds[o000 * 4 + NC] + w001 * lds[o001 * 4 + NC] +
              w010 * lds[o010 * 4 + NC] + w011 * lds[o011 * 4 + NC] +
              w100 * lds[o100 * 4 + NC] + w101 * lds[o101 * 4 + NC] +
              w110 * lds[o110 * 4 + NC] + w111 * lds[o111 * 4 + NC];
  float rinv = 1.0f / fmaxf(den, 1e-8f);
  const float4* L = (const float4*)lds;
  float* op = out + ((size_t)(b * NC) << 18) + (size_t)h * WH + w;
#pragma unroll 2
  for (int g = 0; g < 32; ++g) {
    float4 a0 = L[o000 + g], a1 = L[o001 + g], a2 = L[o010 + g], a3 = L[o011 + g];
    float4 a4 = L[o100 + g], a5 = L[o101 + g], a6 = L[o110 + g], a7 = L[o111 + g];
    float vx = w000 * a0.x + w001 * a1.x + w010 * a2.x + w011 * a3.x +
               w100 * a4.x + w101 * a5.x + w110 * a6.x + w111 * a7.x;
    float vy = w000 * a0.y + w001 * a1.y + w010 * a2.y + w011 * a3.y +
               w100 * a4.y + w101 * a5.y + w110 * a6.y + w111 * a7.y;
    float vz = w000 * a0.z + w001 * a1.z + w010 * a2.z + w011 * a3.z +
               w100 * a4.z + w101 * a5.z + w110 * a6.z + w111 * a7.z;
    float vw = w000 * a0.w + w001 * a1.w + w010 * a2.w + w011 * a3.w +
               w100 * a4.w + w101 * a5.w + w110 * a6.w + w111 * a7.w;
    float* o0 = op + ((size_t)(4 * g) << 18);
    __builtin_nontemporal_store(vx * rinv, o0);
    __builtin_nontemporal_store(vy * rinv, o0 + ((size_t)1 << 18));
    __builtin_nontemporal_store(vz * rinv, o0 + ((size_t)2 << 18));
    __builtin_nontemporal_store(vw * rinv, o0 + ((size_t)3 << 18));
  }
}

extern "C" void kernel_launch(void* const* d_in, const int* in_sizes, int n_in,
                              void* d_out, int out_size, void* d_ws, size_t ws_size,
                              hipStream_t stream) {
  const float* feat   = (const float*)d_in[0];  // (2,128,32,32)
  const float* guide  = (const float*)d_in[1];  // (2,3,512,512)
  const float* sx_raw = (const float*)d_in[2];  // (1,1,32,32)
  const float* sy_raw = (const float*)d_in[3];  // (1,1,32,32)
  // d_in[4] = th_raw: unused by the output
  const float* sr_raw = (const float*)d_in[5];  // (1,1,32,32)
  float* out = (float*)d_out;

  char* ws = (char*)d_ws;
  float* luma_hr = (float*)ws;                                  // 524288 floats (2 MB)
  float* luma_lr = (float*)(ws + (size_t)524288 * 4);           // 2048 floats
  float* grid    = (float*)(ws + (size_t)524288 * 4 + 2048 * 4);// 2*12*32*32*132 floats (~13 MB)

  k_luma<<<2048, 256, 0, stream>>>(guide, luma_hr);
  k_down<<<8, 256, 0, stream>>>(luma_hr, luma_lr);
  k_grid<<<2048, 128, 0, stream>>>(feat, luma_lr, sx_raw, sy_raw, sr_raw, grid);
  k_slice<<<1024, 512, 0, stream>>>(grid, luma_hr, out);
}

// Round 4
// 121.123 us; speedup vs baseline: 1.4597x; 1.2930x over previous
//
#include <hip/hip_runtime.h>

#define HL 32
#define WL 32
#define HH 512
#define WH 512
#define NB 12
#define NC 128
#define CPAD 132      // cell stride in floats (global AND lds) = 33 float4
#define NCELL 144     // 3 rows x 4 cols x 12 z
#define TH 16
#define TW 32

// ---------------- kernel A: luma_hr = mean over 3 guide channels ----------
__global__ void k_luma(const float* __restrict__ guide, float* __restrict__ luma) {
  int i = blockIdx.x * 256 + threadIdx.x;
  if (i >= 2 * HH * WH) return;
  int b = i >> 18;
  int p = i & ((1 << 18) - 1);
  const float* g = guide + ((size_t)b * 3 << 18) + p;
  luma[i] = (g[0] + g[1 << 18] + g[2 << 18]) / 3.0f;
}

// ---------------- kernel B: resize 512->32 bilinear+antialias, wave/output -
__global__ __launch_bounds__(256) void k_down(const float* __restrict__ luma_hr,
                                              float* __restrict__ luma_lr) {
  int o = blockIdx.x * 4 + (threadIdx.x >> 6);
  if (o >= 2 * HL * WL) return;
  int b = o >> 10;
  int r = o & 1023;
  int oy = r >> 5, ox = r & 31;
  int lane = threadIdx.x & 63;
  int ty = lane >> 1, xh = lane & 1;          // 32 rows x 2 x-halves
  float posy = 16.f * oy + 7.5f;
  float posx = 16.f * ox + 7.5f;
  int jy = 16 * oy - 8 + ty;
  float wy = 0.f;
  if (jy >= 0 && jy < HH) wy = 1.f - fabsf((float)jy - posy) * (1.f / 16.f);
  int jyc = min(max(jy, 0), HH - 1);
  const float* row = luma_hr + ((size_t)b << 18) + (size_t)jyc * WH;
  int jx0 = 16 * ox - 8 + xh * 16;
  float num = 0.f, wxs = 0.f;
#pragma unroll
  for (int g = 0; g < 4; ++g) {
    int jxb = jx0 + g * 4;                    // OOB spans are multiples of 4
    int jxc = min(max(jxb, 0), WH - 4);
    float4 vals = *(const float4*)(row + jxc);
#pragma unroll
    for (int k = 0; k < 4; ++k) {
      int jx = jxb + k;
      float wx = 0.f;
      if (jx >= 0 && jx < WH) wx = 1.f - fabsf((float)jx - posx) * (1.f / 16.f);
      float val = (k == 0) ? vals.x : (k == 1) ? vals.y : (k == 2) ? vals.z : vals.w;
      num += wx * val;                        // clamped garbage * wx=0 -> 0
      wxs += wx;
    }
  }
  float pn = wy * num;
  float pd = wy * wxs;                        // sum(wy*wx) = sumy*sumx
#pragma unroll
  for (int m = 1; m < 64; m <<= 1) {
    pn += __shfl_xor(pn, m);
    pd += __shfl_xor(pd, m);
  }
  if (lane == 0) luma_lr[o] = pn / pd;
}

// ---------------- kernel C: build box-filtered bilateral grid -------------
__global__ void k_grid(const float* __restrict__ feat, const float* __restrict__ luma_lr,
                       const float* __restrict__ sx_raw, const float* __restrict__ sy_raw,
                       const float* __restrict__ sr_raw, float* __restrict__ grid) {
  int bid = blockIdx.x;                 // b*1024 + y*32 + x
  int b = bid >> 10;
  int yx = bid & 1023;
  int y = yx >> 5, x = yx & 31;
  __shared__ float wsm[NB * 9];
  int t = threadIdx.x;                  // 128 threads
  if (t < NB * 9) {
    int k = t / 9;
    int j = t - k * 9;
    int dy = j / 3 - 1, dx = (j % 3) - 1;
    int yy = y + dy, xx = x + dx;
    float wv = 0.f;
    if (yy >= 0 && yy < HL && xx >= 0 && xx < WL) {
      int p = yy * WL + xx;
      float lum = luma_lr[b * (HL * WL) + p];
      float dn = expf(sr_raw[p]) * 12.0f + 1e-5f;
      float d = fabsf(lum * 11.0f - (float)k);
      wv = fmaxf(1.0f - d / dn, 0.0f);
    }
    wsm[t] = wv;
  }
  __syncthreads();
  int p0 = y * WL + x;
  float scale = (1.0f + 0.01f * (expf(sx_raw[p0]) + expf(sy_raw[p0]))) * (1.0f / 9.0f);
  float f[9];
  const float* fb = feat + ((size_t)(b * NC) + t) * (HL * WL);
#pragma unroll
  for (int j = 0; j < 9; ++j) {
    int dy = j / 3 - 1, dx = (j % 3) - 1;
    int yy = y + dy, xx = x + dx;
    f[j] = (yy >= 0 && yy < HL && xx >= 0 && xx < WL) ? fb[yy * WL + xx] : 0.f;
  }
#pragma unroll 1
  for (int z = 0; z < NB; ++z) {
    float acc = 0.f;
#pragma unroll
    for (int j = 0; j < 9; ++j) acc += f[j] * wsm[z * 9 + j];
    grid[(((size_t)(b * NB + z) * HL + y) * WL + x) * CPAD + t] = acc * scale;
  }
  if (t < NB) {
    float s = 0.f;
#pragma unroll
    for (int j = 0; j < 9; ++j) s += wsm[t * 9 + j];
    grid[(((size_t)(b * NB + t) * HL + y) * WL + x) * CPAD + NC] = s * scale;
  }
}

// ---------------- kernel D: slice, channel-vector lanes -------------------
// Phase 1 (lanes=pixels): per-pixel weights*rinv + packed cell offsets -> prm.
// Phase 2 (lanes = 8 px-octets x 8 channel-float4): conflict-free b128 corner
// reads; results transposed through trs[] for coalesced channel-plane stores.
__global__ __launch_bounds__(512) void k_slice(const float* __restrict__ grid,
                                               const float* __restrict__ luma_hr,
                                               float* __restrict__ out) {
  __shared__ __align__(16) float glds[NCELL * CPAD];   // 76032 B
  __shared__ __align__(16) float prm[256 * 12];        // 12288 B
  __shared__ __align__(16) float trs[256 * 36];        // 36864 B (padded stride)
  int bid = blockIdx.x;                 // 1024 blocks: b(2) x th(32) x tw(16)
  int b = bid >> 9;
  int t = bid & 511;
  int th = t >> 4, tw = t & 15;
  int h0 = th * TH, w0 = tw * TW;
  int fy = (h0 * 31) / 511;
  int fx = (w0 * 31) / 511;
  int tid = threadIdx.x;

  // --- stage footprint (float4, cellL = (ry*4+rx)*12 + z, stride 33 f4) ---
  {
    const float4* __restrict__ g4 = (const float4*)grid;
    float4* l4 = (float4*)glds;
#pragma unroll 1
    for (int i = tid; i < NCELL * 33; i += 512) {
      int cellL = i / 33;
      int q = i - cellL * 33;
      int rr = cellL / 12;
      int z = cellL - rr * 12;
      int ry = rr >> 2, rx = rr & 3;
      int gy = min(fy + ry, HL - 1);
      int gx = min(fx + rx, WL - 1);
      l4[i] = g4[(((size_t)(b * NB + z) * HL + gy) * WL + gx) * 33 + q];
    }
  }

  const float SCC = 31.0f / 511.0f;
  int wv = tid >> 6;          // wave 0..7 -> row within half
  int lane = tid & 63;
  int oct = lane >> 3, c4 = lane & 7;

#pragma unroll 1
  for (int half = 0; half < 2; ++half) {
    __syncthreads();
    // ---- phase 1: per-pixel params (256 px of this half) ----
    if (tid < 256) {
      int row = tid >> 5, lw = tid & 31;
      int h = h0 + half * 8 + row, w = w0 + lw;
      float luma = luma_hr[((size_t)b << 18) + h * WH + w];
      float u = fminf((float)w * SCC, 31.0f);
      float v = fminf((float)h * SCC, 31.0f);
      float wz = fminf(fmaxf(luma * 11.0f, 0.0f), 11.0f);
      int x0 = (int)u; float fxw = u - (float)x0; int x1 = min(x0 + 1, WL - 1);
      int y0 = (int)v; float fyw = v - (float)y0; int y1 = min(y0 + 1, HL - 1);
      int z0 = (int)wz; float fzw = wz - (float)z0; int z1 = min(z0 + 1, NB - 1);
      int rx0 = min(x0 - fx, 3), rx1 = min(x1 - fx, 3);
      int ry0 = min(y0 - fy, 2), ry1 = min(y1 - fy, 2);
      // packed offsets in float4 units: cell base = (ry*4+rx)*396 + z*33
      int c00 = (ry0 * 4 + rx0) * 396, c01 = (ry0 * 4 + rx1) * 396;
      int c10 = (ry1 * 4 + rx0) * 396, c11 = (ry1 * 4 + rx1) * 396;
      int z0q = z0 * 33, z1q = z1 * 33;
      float x0w = 1.f - fxw, x1w = fxw;
      float y0w = 1.f - fyw, y1w = fyw;
      float z0w = 1.f - fzw, z1w = fzw;
      float wt[8];
      wt[0] = z0w * y0w * x0w; wt[1] = z0w * y0w * x1w;
      wt[2] = z0w * y1w * x0w; wt[3] = z0w * y1w * x1w;
      wt[4] = z1w * y0w * x0w; wt[5] = z1w * y0w * x1w;
      wt[6] = z1w * y1w * x0w; wt[7] = z1w * y1w * x1w;
      int o[8] = {c00 + z0q, c01 + z0q, c10 + z0q, c11 + z0q,
                  c00 + z1q, c01 + z1q, c10 + z1q, c11 + z1q};
      float den = 0.f;
#pragma unroll
      for (int i = 0; i < 8; ++i) den += wt[i] * glds[o[i] * 4 + NC];
      float rinv = 1.0f / fmaxf(den, 1e-8f);
      int pb = tid * 12;
#pragma unroll
      for (int i = 0; i < 8; ++i) prm[pb + i] = wt[i] * rinv;
      unsigned* pu = (unsigned*)prm;
      pu[pb + 8]  = (unsigned)c00 | ((unsigned)c01 << 16);
      pu[pb + 9]  = (unsigned)c10 | ((unsigned)c11 << 16);
      pu[pb + 10] = (unsigned)z0q | ((unsigned)z1q << 16);
    }
    __syncthreads();
    // ---- phase 2: wave wv handles row wv of this half ----
    int h = h0 + half * 8 + wv;
    const float4* __restrict__ G = (const float4*)glds;
#pragma unroll 1
    for (int cc = 0; cc < 4; ++cc) {
#pragma unroll 2
      for (int pg = 0; pg < 4; ++pg) {
        int pxl = wv * 32 + pg * 8 + oct;
        const float4* P = (const float4*)(prm + pxl * 12);
        float4 wA = P[0];
        float4 wB = P[1];
        uint4 pk = ((const uint4*)P)[2];
        int c00 = pk.x & 0xffff, c01 = (int)(pk.x >> 16);
        int c10 = pk.y & 0xffff, c11 = (int)(pk.y >> 16);
        int z0q = pk.z & 0xffff, z1q = (int)(pk.z >> 16);
        int cb = cc * 8 + c4;
        float4 a0 = G[c00 + z0q + cb];
        float4 a1 = G[c01 + z0q + cb];
        float4 a2 = G[c10 + z0q + cb];
        float4 a3 = G[c11 + z0q + cb];
        float4 a4 = G[c00 + z1q + cb];
        float4 a5 = G[c01 + z1q + cb];
        float4 a6 = G[c10 + z1q + cb];
        float4 a7 = G[c11 + z1q + cb];
        float4 acc;
        acc.x = wA.x*a0.x + wA.y*a1.x + wA.z*a2.x + wA.w*a3.x +
                wB.x*a4.x + wB.y*a5.x + wB.z*a6.x + wB.w*a7.x;
        acc.y = wA.x*a0.y + wA.y*a1.y + wA.z*a2.y + wA.w*a3.y +
                wB.x*a4.y + wB.y*a5.y + wB.z*a6.y + wB.w*a7.y;
        acc.z = wA.x*a0.z + wA.y*a1.z + wA.z*a2.z + wA.w*a3.z +
                wB.x*a4.z + wB.y*a5.z + wB.z*a6.z + wB.w*a7.z;
        acc.w = wA.x*a0.w + wA.y*a1.w + wA.z*a2.w + wA.w*a3.w +
                wB.x*a4.w + wB.y*a5.w + wB.z*a6.w + wB.w*a7.w;
        *(float4*)(trs + pxl * 36 + c4 * 4) = acc;
      }
      asm volatile("s_waitcnt lgkmcnt(0)" ::: "memory");
      // store pass: 32 channels (this cc) x 32 px of this wave's row
      {
        int px31 = lane & 31;
        int c2 = lane >> 5;
        int pxl = wv * 32 + px31;
        float* opb = out + ((size_t)(b * NC + cc * 32 + c2) << 18) +
                     (size_t)h * WH + w0 + px31;
#pragma unroll
        for (int s = 0; s < 16; ++s) {
          float val = trs[pxl * 36 + (s * 2 + c2)];
          __builtin_nontemporal_store(val, opb + ((size_t)(s * 2) << 18));
        }
      }
    }
  }
}

extern "C" void kernel_launch(void* const* d_in, const int* in_sizes, int n_in,
                              void* d_out, int out_size, void* d_ws, size_t ws_size,
                              hipStream_t stream) {
  const float* feat   = (const float*)d_in[0];  // (2,128,32,32)
  const float* guide  = (const float*)d_in[1];  // (2,3,512,512)
  const float* sx_raw = (const float*)d_in[2];  // (1,1,32,32)
  const float* sy_raw = (const float*)d_in[3];  // (1,1,32,32)
  // d_in[4] = th_raw: unused by the output
  const float* sr_raw = (const float*)d_in[5];  // (1,1,32,32)
  float* out = (float*)d_out;

  char* ws = (char*)d_ws;
  float* luma_hr = (float*)ws;                                  // 2 MB
  float* luma_lr = (float*)(ws + (size_t)524288 * 4);           // 8 KB
  float* grid    = (float*)(ws + (size_t)524288 * 4 + 2048 * 4);// ~13 MB

  k_luma<<<2048, 256, 0, stream>>>(guide, luma_hr);
  k_down<<<512, 256, 0, stream>>>(luma_hr, luma_lr);
  k_grid<<<2048, 128, 0, stream>>>(feat, luma_lr, sx_raw, sy_raw, sr_raw, grid);
  k_slice<<<1024, 512, 0, stream>>>(grid, luma_hr, out);
}

// Round 5
// 87.034 us; speedup vs baseline: 2.0315x; 1.3917x over previous
//
#include <hip/hip_runtime.h>
#include <hip/hip_fp16.h>

#define HL 32
#define WL 32
#define HH 512
#define WH 512
#define NB 12
#define NC 128
#define TH 16
#define TW 32
#define NCELL 144          // 12 (ry,rx) x 12 z
#define LSTRIDE 17         // LDS cell stride in uint4 (16 data + 1 pad)

// ---------------- kernel A: luma_hr = mean over 3 guide channels ----------
__global__ void k_luma(const float* __restrict__ guide, float* __restrict__ luma) {
  int i = blockIdx.x * 256 + threadIdx.x;
  if (i >= 2 * HH * WH) return;
  int b = i >> 18;
  int p = i & ((1 << 18) - 1);
  const float* g = guide + ((size_t)b * 3 << 18) + p;
  luma[i] = (g[0] + g[1 << 18] + g[2 << 18]) / 3.0f;
}

// ---------------- kernel B: resize 512->32 bilinear+antialias, wave/output -
__global__ __launch_bounds__(256) void k_down(const float* __restrict__ luma_hr,
                                              float* __restrict__ luma_lr) {
  int o = blockIdx.x * 4 + (threadIdx.x >> 6);
  if (o >= 2 * HL * WL) return;
  int b = o >> 10;
  int r = o & 1023;
  int oy = r >> 5, ox = r & 31;
  int lane = threadIdx.x & 63;
  int ty = lane >> 1, xh = lane & 1;
  float posy = 16.f * oy + 7.5f;
  float posx = 16.f * ox + 7.5f;
  int jy = 16 * oy - 8 + ty;
  float wy = 0.f;
  if (jy >= 0 && jy < HH) wy = 1.f - fabsf((float)jy - posy) * (1.f / 16.f);
  int jyc = min(max(jy, 0), HH - 1);
  const float* row = luma_hr + ((size_t)b << 18) + (size_t)jyc * WH;
  int jx0 = 16 * ox - 8 + xh * 16;
  float num = 0.f, wxs = 0.f;
#pragma unroll
  for (int g = 0; g < 4; ++g) {
    int jxb = jx0 + g * 4;
    int jxc = min(max(jxb, 0), WH - 4);
    float4 vals = *(const float4*)(row + jxc);
#pragma unroll
    for (int k = 0; k < 4; ++k) {
      int jx = jxb + k;
      float wx = 0.f;
      if (jx >= 0 && jx < WH) wx = 1.f - fabsf((float)jx - posx) * (1.f / 16.f);
      float val = (k == 0) ? vals.x : (k == 1) ? vals.y : (k == 2) ? vals.z : vals.w;
      num += wx * val;
      wxs += wx;
    }
  }
  float pn = wy * num;
  float pd = wy * wxs;
#pragma unroll
  for (int m = 1; m < 64; m <<= 1) {
    pn += __shfl_xor(pn, m);
    pd += __shfl_xor(pd, m);
  }
  if (lane == 0) luma_lr[o] = pn / pd;
}

// ---------------- kernel C: build box-filtered bilateral grid (fp16) ------
// gridh[b][z][y][x][c] fp16, value = num * 1024 ; den[b][z][y][x] f32 unscaled.
__global__ void k_grid(const float* __restrict__ feat, const float* __restrict__ luma_lr,
                       const float* __restrict__ sx_raw, const float* __restrict__ sy_raw,
                       const float* __restrict__ sr_raw, __half* __restrict__ gridh,
                       float* __restrict__ den) {
  int bid = blockIdx.x;                 // b*1024 + y*32 + x
  int b = bid >> 10;
  int yx = bid & 1023;
  int y = yx >> 5, x = yx & 31;
  __shared__ float wsm[NB * 9];
  int t = threadIdx.x;                  // 128 threads
  if (t < NB * 9) {
    int k = t / 9;
    int j = t - k * 9;
    int dy = j / 3 - 1, dx = (j % 3) - 1;
    int yy = y + dy, xx = x + dx;
    float wv = 0.f;
    if (yy >= 0 && yy < HL && xx >= 0 && xx < WL) {
      int p = yy * WL + xx;
      float lum = luma_lr[b * (HL * WL) + p];
      float dn = expf(sr_raw[p]) * 12.0f + 1e-5f;
      float d = fabsf(lum * 11.0f - (float)k);
      wv = fmaxf(1.0f - d / dn, 0.0f);
    }
    wsm[t] = wv;
  }
  __syncthreads();
  int p0 = y * WL + x;
  float scale = (1.0f + 0.01f * (expf(sx_raw[p0]) + expf(sy_raw[p0]))) * (1.0f / 9.0f);
  float scale1024 = scale * 1024.0f;
  float f[9];
  const float* fb = feat + ((size_t)(b * NC) + t) * (HL * WL);
#pragma unroll
  for (int j = 0; j < 9; ++j) {
    int dy = j / 3 - 1, dx = (j % 3) - 1;
    int yy = y + dy, xx = x + dx;
    f[j] = (yy >= 0 && yy < HL && xx >= 0 && xx < WL) ? fb[yy * WL + xx] : 0.f;
  }
#pragma unroll 1
  for (int z = 0; z < NB; ++z) {
    float acc = 0.f;
#pragma unroll
    for (int j = 0; j < 9; ++j) acc += f[j] * wsm[z * 9 + j];
    gridh[(size_t)(((b * NB + z) * HL + y) * WL + x) * NC + t] = __float2half(acc * scale1024);
  }
  if (t < NB) {
    float s = 0.f;
#pragma unroll
    for (int j = 0; j < 9; ++j) s += wsm[t * 9 + j];
    den[(size_t)(b * NB + t) * (HL * WL) + p0] = s * scale;
  }
}

// ---------------- kernel D: slice, thread-per-pixel, fp16 LDS grid --------
__global__ __launch_bounds__(512) void k_slice(const uint4* __restrict__ grid4,
                                               const float* __restrict__ den,
                                               const float* __restrict__ luma_hr,
                                               float* __restrict__ out) {
  __shared__ uint4 glds[NCELL * LSTRIDE];   // 144*17*16 = 39168 B
  __shared__ float denL[NCELL];
  int bid = blockIdx.x;                 // 1024 blocks: b(2) x th(32) x tw(16)
  int b = bid >> 9;
  int t = bid & 511;
  int th = t >> 4, tw = t & 15;
  int h0 = th * TH, w0 = tw * TW;
  int fy = (h0 * 31) / 511;
  int fx = (w0 * 31) / 511;
  int tid = threadIdx.x;

  // --- stage fp16 grid footprint: cellL = (ry*4+rx)*12 + z ---
#pragma unroll 1
  for (int i = tid; i < NCELL * 16; i += 512) {
    int cellL = i >> 4, q = i & 15;
    int rr = cellL / 12;
    int z = cellL - rr * 12;
    int ry = rr >> 2, rx = rr & 3;
    int gy = min(fy + ry, HL - 1);
    int gx = min(fx + rx, WL - 1);
    glds[cellL * LSTRIDE + q] = grid4[(size_t)(((b * NB + z) * HL + gy) * WL + gx) * 16 + q];
  }
  if (tid < NCELL) {
    int rr = tid / 12;
    int z = tid - rr * 12;
    int ry = rr >> 2, rx = rr & 3;
    int gy = min(fy + ry, HL - 1);
    int gx = min(fx + rx, WL - 1);
    denL[tid] = den[(size_t)(b * NB + z) * (HL * WL) + gy * WL + gx];
  }
  __syncthreads();

  // --- per-pixel params (thread = pixel) ---
  const float SCC = 31.0f / 511.0f;
  int lh = tid >> 5, lw = tid & 31;
  int h = h0 + lh, w = w0 + lw;
  float luma = luma_hr[((size_t)b << 18) + h * WH + w];
  float u = fminf((float)w * SCC, 31.0f);
  float v = fminf((float)h * SCC, 31.0f);
  float wz = fminf(fmaxf(luma * 11.0f, 0.0f), 11.0f);
  int x0 = (int)u; float fxw = u - (float)x0; int x1 = min(x0 + 1, WL - 1);
  int y0 = (int)v; float fyw = v - (float)y0; int y1 = min(y0 + 1, HL - 1);
  int z0 = (int)wz; float fzw = wz - (float)z0; int z1 = min(z0 + 1, NB - 1);
  int rx0 = x0 - fx, rx1 = min(x1 - fx, 3);
  int ry0 = y0 - fy, ry1 = min(y1 - fy, 2);
  int c00 = (ry0 * 4 + rx0) * 12, c01 = (ry0 * 4 + rx1) * 12;
  int c10 = (ry1 * 4 + rx0) * 12, c11 = (ry1 * 4 + rx1) * 12;
  float x0w = 1.f - fxw, x1w = fxw;
  float y0w = 1.f - fyw, y1w = fyw;
  float z0w = 1.f - fzw, z1w = fzw;
  int idx[8] = {c00 + z0, c01 + z0, c10 + z0, c11 + z0,
                c00 + z1, c01 + z1, c10 + z1, c11 + z1};
  float wt[8];
  wt[0] = z0w * y0w * x0w; wt[1] = z0w * y0w * x1w;
  wt[2] = z0w * y1w * x0w; wt[3] = z0w * y1w * x1w;
  wt[4] = z1w * y0w * x0w; wt[5] = z1w * y0w * x1w;
  wt[6] = z1w * y1w * x0w; wt[7] = z1w * y1w * x1w;
  float dv = 0.f;
#pragma unroll
  for (int k = 0; k < 8; ++k) dv += wt[k] * denL[idx[k]];
  float rinv = 1.0f / (1024.0f * fmaxf(dv, 1e-8f));
  float wk[8];
  int off[8];
#pragma unroll
  for (int k = 0; k < 8; ++k) { wk[k] = wt[k] * rinv; off[k] = idx[k] * LSTRIDE; }

  float* opb = out + ((size_t)(b * NC) << 18) + (size_t)h * WH + w;
  // --- 16 channel-octets: 8 corner b128 reads, 64 mixed FMAs, 8 nt stores ---
#pragma unroll 1
  for (int cw = 0; cw < 16; ++cw) {
    float a0 = 0.f, a1 = 0.f, a2 = 0.f, a3 = 0.f, a4 = 0.f, a5 = 0.f, a6 = 0.f, a7 = 0.f;
#pragma unroll
    for (int k = 0; k < 8; ++k) {
      uint4 q = glds[off[k] + cw];
      const __half2* hp = (const __half2*)&q;
      float wkk = wk[k];
      float2 f0 = __half22float2(hp[0]);
      float2 f1 = __half22float2(hp[1]);
      float2 f2 = __half22float2(hp[2]);
      float2 f3 = __half22float2(hp[3]);
      a0 += wkk * f0.x; a1 += wkk * f0.y;
      a2 += wkk * f1.x; a3 += wkk * f1.y;
      a4 += wkk * f2.x; a5 += wkk * f2.y;
      a6 += wkk * f3.x; a7 += wkk * f3.y;
    }
    float* o0 = opb + ((size_t)(cw * 8) << 18);
    __builtin_nontemporal_store(a0, o0);
    __builtin_nontemporal_store(a1, o0 + ((size_t)1 << 18));
    __builtin_nontemporal_store(a2, o0 + ((size_t)2 << 18));
    __builtin_nontemporal_store(a3, o0 + ((size_t)3 << 18));
    __builtin_nontemporal_store(a4, o0 + ((size_t)4 << 18));
    __builtin_nontemporal_store(a5, o0 + ((size_t)5 << 18));
    __builtin_nontemporal_store(a6, o0 + ((size_t)6 << 18));
    __builtin_nontemporal_store(a7, o0 + ((size_t)7 << 18));
  }
}

extern "C" void kernel_launch(void* const* d_in, const int* in_sizes, int n_in,
                              void* d_out, int out_size, void* d_ws, size_t ws_size,
                              hipStream_t stream) {
  const float* feat   = (const float*)d_in[0];  // (2,128,32,32)
  const float* guide  = (const float*)d_in[1];  // (2,3,512,512)
  const float* sx_raw = (const float*)d_in[2];  // (1,1,32,32)
  const float* sy_raw = (const float*)d_in[3];  // (1,1,32,32)
  // d_in[4] = th_raw: unused by the output
  const float* sr_raw = (const float*)d_in[5];  // (1,1,32,32)
  float* out = (float*)d_out;

  char* ws = (char*)d_ws;
  float*  luma_hr = (float*)ws;                         // 2 MB
  float*  luma_lr = (float*)(ws + 2097152);             // 8 KB
  float*  den     = (float*)(ws + 2097152 + 8192);      // 96 KB
  __half* gridh   = (__half*)(ws + 2097152 + 8192 + 98304); // 6 MB (16B aligned)

  k_luma<<<2048, 256, 0, stream>>>(guide, luma_hr);
  k_down<<<512, 256, 0, stream>>>(luma_hr, luma_lr);
  k_grid<<<2048, 128, 0, stream>>>(feat, luma_lr, sx_raw, sy_raw, sr_raw, gridh, den);
  k_slice<<<1024, 512, 0, stream>>>((const uint4*)gridh, den, luma_hr, out);
}

// Round 6
// 83.761 us; speedup vs baseline: 2.1108x; 1.0391x over previous
//
#include <hip/hip_runtime.h>
#include <hip/hip_fp16.h>

#define HL 32
#define WL 32
#define HH 512
#define WH 512
#define NB 12
#define NC 128
#define TH 16
#define TW 32
#define NCELL 144          // 12 (ry,rx) x 12 z
#define LSTRIDE 17         // LDS cell stride in uint4 (16 data + 1 pad)
#define PLANE 262144       // HH*WH

// swizzle: spreads cells z and z+8 (bank-aliased at stride 68 dwords) apart
__device__ __forceinline__ int swz(int cell) { return ((cell >> 3) & 1) << 2; }

// ---------------- kernel B: resize 512->32 bilinear+antialias -------------
// Reads guide directly (mean over channels inline; mean/resize commute and
// the reference also averages first). One wave per output.
__global__ __launch_bounds__(256) void k_down(const float* __restrict__ guide,
                                              float* __restrict__ luma_lr) {
  int o = blockIdx.x * 4 + (threadIdx.x >> 6);
  if (o >= 2 * HL * WL) return;
  int b = o >> 10;
  int r = o & 1023;
  int oy = r >> 5, ox = r & 31;
  int lane = threadIdx.x & 63;
  int ty = lane >> 1, xh = lane & 1;
  float posy = 16.f * oy + 7.5f;
  float posx = 16.f * ox + 7.5f;
  int jy = 16 * oy - 8 + ty;
  float wy = 0.f;
  if (jy >= 0 && jy < HH) wy = 1.f - fabsf((float)jy - posy) * (1.f / 16.f);
  int jyc = min(max(jy, 0), HH - 1);
  const float* row = guide + (size_t)b * 3 * PLANE + (size_t)jyc * WH;
  int jx0 = 16 * ox - 8 + xh * 16;
  float num = 0.f, wxs = 0.f;
#pragma unroll
  for (int g = 0; g < 4; ++g) {
    int jxb = jx0 + g * 4;
    int jxc = min(max(jxb, 0), WH - 4);
    float4 v0 = *(const float4*)(row + jxc);
    float4 v1 = *(const float4*)(row + PLANE + jxc);
    float4 v2 = *(const float4*)(row + 2 * PLANE + jxc);
#pragma unroll
    for (int k = 0; k < 4; ++k) {
      int jx = jxb + k;
      float wx = 0.f;
      if (jx >= 0 && jx < WH) wx = 1.f - fabsf((float)jx - posx) * (1.f / 16.f);
      float a = (k == 0) ? v0.x : (k == 1) ? v0.y : (k == 2) ? v0.z : v0.w;
      float bb = (k == 0) ? v1.x : (k == 1) ? v1.y : (k == 2) ? v1.z : v1.w;
      float c = (k == 0) ? v2.x : (k == 1) ? v2.y : (k == 2) ? v2.z : v2.w;
      num += wx * ((a + bb + c) * (1.0f / 3.0f));
      wxs += wx;
    }
  }
  float pn = wy * num;
  float pd = wy * wxs;
#pragma unroll
  for (int m = 1; m < 64; m <<= 1) {
    pn += __shfl_xor(pn, m);
    pd += __shfl_xor(pd, m);
  }
  if (lane == 0) luma_lr[o] = pn / pd;
}

// ---------------- kernel C: build box-filtered bilateral grid (fp16) ------
__global__ void k_grid(const float* __restrict__ feat, const float* __restrict__ luma_lr,
                       const float* __restrict__ sx_raw, const float* __restrict__ sy_raw,
                       const float* __restrict__ sr_raw, __half* __restrict__ gridh,
                       float* __restrict__ den) {
  int bid = blockIdx.x;                 // b*1024 + y*32 + x
  int b = bid >> 10;
  int yx = bid & 1023;
  int y = yx >> 5, x = yx & 31;
  __shared__ float wsm[NB * 9];
  int t = threadIdx.x;                  // 128 threads
  if (t < NB * 9) {
    int k = t / 9;
    int j = t - k * 9;
    int dy = j / 3 - 1, dx = (j % 3) - 1;
    int yy = y + dy, xx = x + dx;
    float wv = 0.f;
    if (yy >= 0 && yy < HL && xx >= 0 && xx < WL) {
      int p = yy * WL + xx;
      float lum = luma_lr[b * (HL * WL) + p];
      float dn = expf(sr_raw[p]) * 12.0f + 1e-5f;
      float d = fabsf(lum * 11.0f - (float)k);
      wv = fmaxf(1.0f - d / dn, 0.0f);
    }
    wsm[t] = wv;
  }
  __syncthreads();
  int p0 = y * WL + x;
  float scale = (1.0f + 0.01f * (expf(sx_raw[p0]) + expf(sy_raw[p0]))) * (1.0f / 9.0f);
  float scale1024 = scale * 1024.0f;
  float f[9];
  const float* fb = feat + ((size_t)(b * NC) + t) * (HL * WL);
#pragma unroll
  for (int j = 0; j < 9; ++j) {
    int dy = j / 3 - 1, dx = (j % 3) - 1;
    int yy = y + dy, xx = x + dx;
    f[j] = (yy >= 0 && yy < HL && xx >= 0 && xx < WL) ? fb[yy * WL + xx] : 0.f;
  }
#pragma unroll 1
  for (int z = 0; z < NB; ++z) {
    float acc = 0.f;
#pragma unroll
    for (int j = 0; j < 9; ++j) acc += f[j] * wsm[z * 9 + j];
    gridh[(size_t)(((b * NB + z) * HL + y) * WL + x) * NC + t] = __float2half(acc * scale1024);
  }
  if (t < NB) {
    float s = 0.f;
#pragma unroll
    for (int j = 0; j < 9; ++j) s += wsm[t * 9 + j];
    den[(size_t)(b * NB + t) * (HL * WL) + p0] = s * scale;
  }
}

// ---------------- kernel D: slice, thread-per-pixel, fp16 LDS grid --------
__global__ __launch_bounds__(512) void k_slice(const uint4* __restrict__ grid4,
                                               const float* __restrict__ den,
                                               const float* __restrict__ guide,
                                               float* __restrict__ out) {
  __shared__ uint4 glds[NCELL * LSTRIDE];   // 144*17*16 = 39168 B
  __shared__ float denL[NCELL];
  int bid = blockIdx.x;                 // 1024 blocks: b(2) x th(32) x tw(16)
  int b = bid >> 9;
  int t = bid & 511;
  int th = t >> 4, tw = t & 15;
  int h0 = th * TH, w0 = tw * TW;
  int fy = (h0 * 31) / 511;
  int fx = (w0 * 31) / 511;
  int tid = threadIdx.x;

  // --- stage fp16 grid footprint: cellL = (ry*4+rx)*12 + z, swizzled q ---
#pragma unroll 1
  for (int i = tid; i < NCELL * 16; i += 512) {
    int cellL = i >> 4, q = i & 15;
    int rr = cellL / 12;
    int z = cellL - rr * 12;
    int ry = rr >> 2, rx = rr & 3;
    int gy = min(fy + ry, HL - 1);
    int gx = min(fx + rx, WL - 1);
    glds[cellL * LSTRIDE + (q ^ swz(cellL))] =
        grid4[(size_t)(((b * NB + z) * HL + gy) * WL + gx) * 16 + q];
  }
  if (tid < NCELL) {
    int rr = tid / 12;
    int z = tid - rr * 12;
    int ry = rr >> 2, rx = rr & 3;
    int gy = min(fy + ry, HL - 1);
    int gx = min(fx + rx, WL - 1);
    denL[tid] = den[(size_t)(b * NB + z) * (HL * WL) + gy * WL + gx];
  }
  __syncthreads();

  // --- per-pixel params (thread = pixel) ---
  const float SCC = 31.0f / 511.0f;
  int lh = tid >> 5, lw = tid & 31;
  int h = h0 + lh, w = w0 + lw;
  const float* gb = guide + (size_t)b * 3 * PLANE + (size_t)h * WH + w;
  float luma = (gb[0] + gb[PLANE] + gb[2 * PLANE]) * (1.0f / 3.0f);
  float u = fminf((float)w * SCC, 31.0f);
  float v = fminf((float)h * SCC, 31.0f);
  float wz = fminf(fmaxf(luma * 11.0f, 0.0f), 11.0f);
  int x0 = (int)u; float fxw = u - (float)x0; int x1 = min(x0 + 1, WL - 1);
  int y0 = (int)v; float fyw = v - (float)y0; int y1 = min(y0 + 1, HL - 1);
  int z0 = (int)wz; float fzw = wz - (float)z0; int z1 = min(z0 + 1, NB - 1);
  int rx0 = x0 - fx, rx1 = min(x1 - fx, 3);
  int ry0 = y0 - fy, ry1 = min(y1 - fy, 2);
  int c00 = (ry0 * 4 + rx0) * 12, c01 = (ry0 * 4 + rx1) * 12;
  int c10 = (ry1 * 4 + rx0) * 12, c11 = (ry1 * 4 + rx1) * 12;
  float x0w = 1.f - fxw, x1w = fxw;
  float y0w = 1.f - fyw, y1w = fyw;
  float z0w = 1.f - fzw, z1w = fzw;
  int idx[8] = {c00 + z0, c01 + z0, c10 + z0, c11 + z0,
                c00 + z1, c01 + z1, c10 + z1, c11 + z1};
  float wt[8];
  wt[0] = z0w * y0w * x0w; wt[1] = z0w * y0w * x1w;
  wt[2] = z0w * y1w * x0w; wt[3] = z0w * y1w * x1w;
  wt[4] = z1w * y0w * x0w; wt[5] = z1w * y0w * x1w;
  wt[6] = z1w * y1w * x0w; wt[7] = z1w * y1w * x1w;
  float dv = 0.f;
#pragma unroll
  for (int k = 0; k < 8; ++k) dv += wt[k] * denL[idx[k]];
  float rinv = 1.0f / (1024.0f * fmaxf(dv, 1e-8f));
  float wk[8];
  int off[8], sw[8];
#pragma unroll
  for (int k = 0; k < 8; ++k) {
    wk[k] = wt[k] * rinv;
    off[k] = idx[k] * LSTRIDE;
    sw[k] = swz(idx[k]);
  }

  float* opb = out + ((size_t)(b * NC) << 18) + (size_t)h * WH + w;
  // --- 16 channel-octets: 8 corner b128 reads, 64 mixed FMAs, 8 nt stores ---
#pragma unroll 1
  for (int cw = 0; cw < 16; ++cw) {
    float a0 = 0.f, a1 = 0.f, a2 = 0.f, a3 = 0.f, a4 = 0.f, a5 = 0.f, a6 = 0.f, a7 = 0.f;
#pragma unroll
    for (int k = 0; k < 8; ++k) {
      uint4 q = glds[off[k] + (cw ^ sw[k])];
      const __half2* hp = (const __half2*)&q;
      float wkk = wk[k];
      float2 f0 = __half22float2(hp[0]);
      float2 f1 = __half22float2(hp[1]);
      float2 f2 = __half22float2(hp[2]);
      float2 f3 = __half22float2(hp[3]);
      a0 += wkk * f0.x; a1 += wkk * f0.y;
      a2 += wkk * f1.x; a3 += wkk * f1.y;
      a4 += wkk * f2.x; a5 += wkk * f2.y;
      a6 += wkk * f3.x; a7 += wkk * f3.y;
    }
    float* o0 = opb + ((size_t)(cw * 8) << 18);
    __builtin_nontemporal_store(a0, o0);
    __builtin_nontemporal_store(a1, o0 + ((size_t)1 << 18));
    __builtin_nontemporal_store(a2, o0 + ((size_t)2 << 18));
    __builtin_nontemporal_store(a3, o0 + ((size_t)3 << 18));
    __builtin_nontemporal_store(a4, o0 + ((size_t)4 << 18));
    __builtin_nontemporal_store(a5, o0 + ((size_t)5 << 18));
    __builtin_nontemporal_store(a6, o0 + ((size_t)6 << 18));
    __builtin_nontemporal_store(a7, o0 + ((size_t)7 << 18));
  }
}

extern "C" void kernel_launch(void* const* d_in, const int* in_sizes, int n_in,
                              void* d_out, int out_size, void* d_ws, size_t ws_size,
                              hipStream_t stream) {
  const float* feat   = (const float*)d_in[0];  // (2,128,32,32)
  const float* guide  = (const float*)d_in[1];  // (2,3,512,512)
  const float* sx_raw = (const float*)d_in[2];  // (1,1,32,32)
  const float* sy_raw = (const float*)d_in[3];  // (1,1,32,32)
  // d_in[4] = th_raw: unused by the output
  const float* sr_raw = (const float*)d_in[5];  // (1,1,32,32)
  float* out = (float*)d_out;

  char* ws = (char*)d_ws;
  float*  luma_lr = (float*)ws;                         // 8 KB
  float*  den     = (float*)(ws + 8192);                // 96 KB
  __half* gridh   = (__half*)(ws + 8192 + 98304);       // 6 MB (16B aligned)

  k_down<<<512, 256, 0, stream>>>(guide, luma_lr);
  k_grid<<<2048, 128, 0, stream>>>(feat, luma_lr, sx_raw, sy_raw, sr_raw, gridh, den);
  k_slice<<<1024, 512, 0, stream>>>((const uint4*)gridh, den, guide, out);
}

// Round 8
// 76.768 us; speedup vs baseline: 2.3031x; 1.0911x over previous
//
#include <hip/hip_runtime.h>
#include <hip/hip_fp16.h>

#define HL 32
#define WL 32
#define HH 512
#define WH 512
#define NB 12
#define NC 128
#define TH 16
#define TW 64
#define NRX 6              // x-cols in footprint
#define NRY 3              // y-rows in footprint
#define NCELL (NRX*NRY*NB) // 216
#define LSTRIDE 17         // LDS cell stride in uint4 (16 data + 1 pad)
#define PLANE 262144       // HH*WH

typedef float f2_t __attribute__((ext_vector_type(2)));

__device__ __forceinline__ int swzf(int cell) { return ((cell >> 3) & 1) << 2; }

// ---------------- kernel B: resize 512->32 bilinear+antialias -------------
__global__ __launch_bounds__(256) void k_down(const float* __restrict__ guide,
                                              float* __restrict__ luma_lr) {
  int o = blockIdx.x * 4 + (threadIdx.x >> 6);
  if (o >= 2 * HL * WL) return;
  int b = o >> 10;
  int r = o & 1023;
  int oy = r >> 5, ox = r & 31;
  int lane = threadIdx.x & 63;
  int ty = lane >> 1, xh = lane & 1;
  float posy = 16.f * oy + 7.5f;
  float posx = 16.f * ox + 7.5f;
  int jy = 16 * oy - 8 + ty;
  float wy = 0.f;
  if (jy >= 0 && jy < HH) wy = 1.f - fabsf((float)jy - posy) * (1.f / 16.f);
  int jyc = min(max(jy, 0), HH - 1);
  const float* row = guide + (size_t)b * 3 * PLANE + (size_t)jyc * WH;
  int jx0 = 16 * ox - 8 + xh * 16;
  float num = 0.f, wxs = 0.f;
#pragma unroll
  for (int g = 0; g < 4; ++g) {
    int jxb = jx0 + g * 4;
    int jxc = min(max(jxb, 0), WH - 4);
    float4 v0 = *(const float4*)(row + jxc);
    float4 v1 = *(const float4*)(row + PLANE + jxc);
    float4 v2 = *(const float4*)(row + 2 * PLANE + jxc);
#pragma unroll
    for (int k = 0; k < 4; ++k) {
      int jx = jxb + k;
      float wx = 0.f;
      if (jx >= 0 && jx < WH) wx = 1.f - fabsf((float)jx - posx) * (1.f / 16.f);
      float a = (k == 0) ? v0.x : (k == 1) ? v0.y : (k == 2) ? v0.z : v0.w;
      float bb = (k == 0) ? v1.x : (k == 1) ? v1.y : (k == 2) ? v1.z : v1.w;
      float c = (k == 0) ? v2.x : (k == 1) ? v2.y : (k == 2) ? v2.z : v2.w;
      num += wx * ((a + bb + c) * (1.0f / 3.0f));
      wxs += wx;
    }
  }
  float pn = wy * num;
  float pd = wy * wxs;
#pragma unroll
  for (int m = 1; m < 64; m <<= 1) {
    pn += __shfl_xor(pn, m);
    pd += __shfl_xor(pd, m);
  }
  if (lane == 0) luma_lr[o] = pn / pd;
}

// ---------------- kernel C: build box-filtered bilateral grid (fp16) ------
__global__ void k_grid(const float* __restrict__ feat, const float* __restrict__ luma_lr,
                       const float* __restrict__ sx_raw, const float* __restrict__ sy_raw,
                       const float* __restrict__ sr_raw, __half* __restrict__ gridh,
                       float* __restrict__ den) {
  int bid = blockIdx.x;                 // b*1024 + y*32 + x
  int b = bid >> 10;
  int yx = bid & 1023;
  int y = yx >> 5, x = yx & 31;
  __shared__ float wsm[NB * 9];
  int t = threadIdx.x;                  // 128 threads
  if (t < NB * 9) {
    int k = t / 9;
    int j = t - k * 9;
    int dy = j / 3 - 1, dx = (j % 3) - 1;
    int yy = y + dy, xx = x + dx;
    float wv = 0.f;
    if (yy >= 0 && yy < HL && xx >= 0 && xx < WL) {
      int p = yy * WL + xx;
      float lum = luma_lr[b * (HL * WL) + p];
      float dn = expf(sr_raw[p]) * 12.0f + 1e-5f;
      float d = fabsf(lum * 11.0f - (float)k);
      wv = fmaxf(1.0f - d / dn, 0.0f);
    }
    wsm[t] = wv;
  }
  __syncthreads();
  int p0 = y * WL + x;
  float scale = (1.0f + 0.01f * (expf(sx_raw[p0]) + expf(sy_raw[p0]))) * (1.0f / 9.0f);
  float scale1024 = scale * 1024.0f;
  float f[9];
  const float* fb = feat + ((size_t)(b * NC) + t) * (HL * WL);
#pragma unroll
  for (int j = 0; j < 9; ++j) {
    int dy = j / 3 - 1, dx = (j % 3) - 1;
    int yy = y + dy, xx = x + dx;
    f[j] = (yy >= 0 && yy < HL && xx >= 0 && xx < WL) ? fb[yy * WL + xx] : 0.f;
  }
#pragma unroll 1
  for (int z = 0; z < NB; ++z) {
    float acc = 0.f;
#pragma unroll
    for (int j = 0; j < 9; ++j) acc += f[j] * wsm[z * 9 + j];
    gridh[(size_t)(((b * NB + z) * HL + y) * WL + x) * NC + t] = __float2half(acc * scale1024);
  }
  if (t < NB) {
    float s = 0.f;
#pragma unroll
    for (int j = 0; j < 9; ++j) s += wsm[t * 9 + j];
    den[(size_t)(b * NB + t) * (HL * WL) + p0] = s * scale;
  }
}

// ---------------- kernel D: slice, 2 px/thread, float2 stores -------------
__global__ __launch_bounds__(512) void k_slice(const uint4* __restrict__ grid4,
                                               const float* __restrict__ den,
                                               const float* __restrict__ guide,
                                               float* __restrict__ out) {
  __shared__ uint4 glds[NCELL * LSTRIDE];   // 216*17*16 = 58752 B
  __shared__ float denL[NCELL];
  int bid = blockIdx.x;                 // 512 blocks: b(2) x th(32) x tw(8)
  int b = bid >> 8;
  int t = bid & 255;
  int th = t >> 3, tw = t & 7;
  int h0 = th * TH, w0 = tw * TW;
  int fy = (h0 * 31) / 511;
  int fx = (w0 * 31) / 511;
  int tid = threadIdx.x;

  // --- stage fp16 grid footprint: cellL = (ry*NRX+rx)*12 + z ---
#pragma unroll 1
  for (int i = tid; i < NCELL * 16; i += 512) {
    int cellL = i >> 4, q = i & 15;
    int rr = cellL / 12;
    int z = cellL - rr * 12;
    int ry = rr / NRX, rx = rr - ry * NRX;
    int gy = min(fy + ry, HL - 1);
    int gx = min(fx + rx, WL - 1);
    glds[cellL * LSTRIDE + (q ^ swzf(cellL))] =
        grid4[(size_t)(((b * NB + z) * HL + gy) * WL + gx) * 16 + q];
  }
  if (tid < NCELL) {
    int rr = tid / 12;
    int z = tid - rr * 12;
    int ry = rr / NRX, rx = rr - ry * NRX;
    int gy = min(fy + ry, HL - 1);
    int gx = min(fx + rx, WL - 1);
    denL[tid] = den[(size_t)(b * NB + z) * (HL * WL) + gy * WL + gx];
  }
  __syncthreads();

  // --- per-pixel params: thread owns 2 adjacent px ---
  const float SCC = 31.0f / 511.0f;
  int lh = tid >> 5;                 // 0..15
  int wp = (tid & 31) * 2;           // even w offset
  int h = h0 + lh;
  float wk_[2][8];
  int off_[2][8], sw_[2][8];
  const float* gb0 = guide + (size_t)b * 3 * PLANE + (size_t)h * WH + w0 + wp;
  float2 g0 = *(const float2*)(gb0);
  float2 g1 = *(const float2*)(gb0 + PLANE);
  float2 g2 = *(const float2*)(gb0 + 2 * PLANE);
#pragma unroll
  for (int p = 0; p < 2; ++p) {
    int w = w0 + wp + p;
    float luma = ((p ? g0.y : g0.x) + (p ? g1.y : g1.x) + (p ? g2.y : g2.x)) * (1.0f / 3.0f);
    float u = fminf((float)w * SCC, 31.0f);
    float v = fminf((float)h * SCC, 31.0f);
    float wz = fminf(fmaxf(luma * 11.0f, 0.0f), 11.0f);
    int x0 = (int)u; float fxw = u - (float)x0; int x1 = min(x0 + 1, WL - 1);
    int y0 = (int)v; float fyw = v - (float)y0; int y1 = min(y0 + 1, HL - 1);
    int z0 = (int)wz; float fzw = wz - (float)z0; int z1 = min(z0 + 1, NB - 1);
    int rx0 = x0 - fx, rx1 = min(x1 - fx, NRX - 1);
    int ry0 = y0 - fy, ry1 = min(y1 - fy, NRY - 1);
    int c00 = (ry0 * NRX + rx0) * 12, c01 = (ry0 * NRX + rx1) * 12;
    int c10 = (ry1 * NRX + rx0) * 12, c11 = (ry1 * NRX + rx1) * 12;
    float x0w = 1.f - fxw, x1w = fxw;
    float y0w = 1.f - fyw, y1w = fyw;
    float z0w = 1.f - fzw, z1w = fzw;
    int idx[8] = {c00 + z0, c01 + z0, c10 + z0, c11 + z0,
                  c00 + z1, c01 + z1, c10 + z1, c11 + z1};
    float wt[8];
    wt[0] = z0w * y0w * x0w; wt[1] = z0w * y0w * x1w;
    wt[2] = z0w * y1w * x0w; wt[3] = z0w * y1w * x1w;
    wt[4] = z1w * y0w * x0w; wt[5] = z1w * y0w * x1w;
    wt[6] = z1w * y1w * x0w; wt[7] = z1w * y1w * x1w;
    float dv = 0.f;
#pragma unroll
    for (int k = 0; k < 8; ++k) dv += wt[k] * denL[idx[k]];
    float rinv = 1.0f / (1024.0f * fmaxf(dv, 1e-8f));
#pragma unroll
    for (int k = 0; k < 8; ++k) {
      wk_[p][k] = wt[k] * rinv;
      off_[p][k] = idx[k] * LSTRIDE;
      sw_[p][k] = swzf(idx[k]);
    }
  }

  float* opb = out + ((size_t)(b * NC) << 18) + (size_t)h * WH + w0 + wp;
  // --- 16 channel-octets: 16 corner b128 reads (2 px), 8 f2 stores --------
#pragma unroll 2
  for (int cw = 0; cw < 16; ++cw) {
    float av[2][8];
#pragma unroll
    for (int p = 0; p < 2; ++p) {
#pragma unroll
      for (int c = 0; c < 8; ++c) av[p][c] = 0.f;
#pragma unroll
      for (int k = 0; k < 8; ++k) {
        uint4 q = glds[off_[p][k] + (cw ^ sw_[p][k])];
        const __half2* hp = (const __half2*)&q;
        float wkk = wk_[p][k];
        float2 f0 = __half22float2(hp[0]);
        float2 f1 = __half22float2(hp[1]);
        float2 f2 = __half22float2(hp[2]);
        float2 f3 = __half22float2(hp[3]);
        av[p][0] += wkk * f0.x; av[p][1] += wkk * f0.y;
        av[p][2] += wkk * f1.x; av[p][3] += wkk * f1.y;
        av[p][4] += wkk * f2.x; av[p][5] += wkk * f2.y;
        av[p][6] += wkk * f3.x; av[p][7] += wkk * f3.y;
      }
    }
    float* o0 = opb + ((size_t)(cw * 8) << 18);
#pragma unroll
    for (int c = 0; c < 8; ++c) {
      f2_t v2;
      v2.x = av[0][c];
      v2.y = av[1][c];
      __builtin_nontemporal_store(v2, (f2_t*)(o0 + ((size_t)c << 18)));
    }
  }
}

extern "C" void kernel_launch(void* const* d_in, const int* in_sizes, int n_in,
                              void* d_out, int out_size, void* d_ws, size_t ws_size,
                              hipStream_t stream) {
  const float* feat   = (const float*)d_in[0];  // (2,128,32,32)
  const float* guide  = (const float*)d_in[1];  // (2,3,512,512)
  const float* sx_raw = (const float*)d_in[2];  // (1,1,32,32)
  const float* sy_raw = (const float*)d_in[3];  // (1,1,32,32)
  // d_in[4] = th_raw: unused by the output
  const float* sr_raw = (const float*)d_in[5];  // (1,1,32,32)
  float* out = (float*)d_out;

  char* ws = (char*)d_ws;
  float*  luma_lr = (float*)ws;                         // 8 KB
  float*  den     = (float*)(ws + 8192);                // 96 KB
  __half* gridh   = (__half*)(ws + 8192 + 98304);       // 6 MB (16B aligned)

  k_down<<<512, 256, 0, stream>>>(guide, luma_lr);
  k_grid<<<2048, 128, 0, stream>>>(feat, luma_lr, sx_raw, sy_raw, sr_raw, gridh, den);
  k_slice<<<512, 512, 0, stream>>>((const uint4*)gridh, den, guide, out);
}

// Round 9
// 68.636 us; speedup vs baseline: 2.5760x; 1.1185x over previous
//
#include <hip/hip_runtime.h>
#include <hip/hip_fp16.h>

#define HL 32
#define WL 32
#define HH 512
#define WH 512
#define NB 12
#define NC 128
#define TH 16
#define TW 64
#define NRX 6              // x-cols in footprint
#define NRY 3              // y-rows in footprint
#define NCELL (NRX*NRY*NB) // 216
#define LSTRIDE 17         // LDS cell stride in uint4 (16 data + 1 pad)
#define PLANE 262144       // HH*WH

typedef float f2_t __attribute__((ext_vector_type(2)));

__device__ __forceinline__ int swzf(int cell) { return ((cell >> 3) & 1) << 2; }

// ---------------- kernel B: resize 512->32 bilinear+antialias -------------
__global__ __launch_bounds__(256) void k_down(const float* __restrict__ guide,
                                              float* __restrict__ luma_lr) {
  int o = blockIdx.x * 4 + (threadIdx.x >> 6);
  if (o >= 2 * HL * WL) return;
  int b = o >> 10;
  int r = o & 1023;
  int oy = r >> 5, ox = r & 31;
  int lane = threadIdx.x & 63;
  int ty = lane >> 1, xh = lane & 1;
  float posy = 16.f * oy + 7.5f;
  float posx = 16.f * ox + 7.5f;
  int jy = 16 * oy - 8 + ty;
  float wy = 0.f;
  if (jy >= 0 && jy < HH) wy = 1.f - fabsf((float)jy - posy) * (1.f / 16.f);
  int jyc = min(max(jy, 0), HH - 1);
  const float* row = guide + (size_t)b * 3 * PLANE + (size_t)jyc * WH;
  int jx0 = 16 * ox - 8 + xh * 16;
  float num = 0.f, wxs = 0.f;
#pragma unroll
  for (int g = 0; g < 4; ++g) {
    int jxb = jx0 + g * 4;
    int jxc = min(max(jxb, 0), WH - 4);
    float4 v0 = *(const float4*)(row + jxc);
    float4 v1 = *(const float4*)(row + PLANE + jxc);
    float4 v2 = *(const float4*)(row + 2 * PLANE + jxc);
#pragma unroll
    for (int k = 0; k < 4; ++k) {
      int jx = jxb + k;
      float wx = 0.f;
      if (jx >= 0 && jx < WH) wx = 1.f - fabsf((float)jx - posx) * (1.f / 16.f);
      float a = (k == 0) ? v0.x : (k == 1) ? v0.y : (k == 2) ? v0.z : v0.w;
      float bb = (k == 0) ? v1.x : (k == 1) ? v1.y : (k == 2) ? v1.z : v1.w;
      float c = (k == 0) ? v2.x : (k == 1) ? v2.y : (k == 2) ? v2.z : v2.w;
      num += wx * ((a + bb + c) * (1.0f / 3.0f));
      wxs += wx;
    }
  }
  float pn = wy * num;
  float pd = wy * wxs;
#pragma unroll
  for (int m = 1; m < 64; m <<= 1) {
    pn += __shfl_xor(pn, m);
    pd += __shfl_xor(pd, m);
  }
  if (lane == 0) luma_lr[o] = pn / pd;
}

// ---------------- kernel C: build box-filtered bilateral grid (fp16) ------
__global__ void k_grid(const float* __restrict__ feat, const float* __restrict__ luma_lr,
                       const float* __restrict__ sx_raw, const float* __restrict__ sy_raw,
                       const float* __restrict__ sr_raw, __half* __restrict__ gridh,
                       float* __restrict__ den) {
  int bid = blockIdx.x;                 // b*1024 + y*32 + x
  int b = bid >> 10;
  int yx = bid & 1023;
  int y = yx >> 5, x = yx & 31;
  __shared__ float wsm[NB * 9];
  int t = threadIdx.x;                  // 128 threads
  if (t < NB * 9) {
    int k = t / 9;
    int j = t - k * 9;
    int dy = j / 3 - 1, dx = (j % 3) - 1;
    int yy = y + dy, xx = x + dx;
    float wv = 0.f;
    if (yy >= 0 && yy < HL && xx >= 0 && xx < WL) {
      int p = yy * WL + xx;
      float lum = luma_lr[b * (HL * WL) + p];
      float dn = expf(sr_raw[p]) * 12.0f + 1e-5f;
      float d = fabsf(lum * 11.0f - (float)k);
      wv = fmaxf(1.0f - d / dn, 0.0f);
    }
    wsm[t] = wv;
  }
  __syncthreads();
  int p0 = y * WL + x;
  float scale = (1.0f + 0.01f * (expf(sx_raw[p0]) + expf(sy_raw[p0]))) * (1.0f / 9.0f);
  float scale1024 = scale * 1024.0f;
  float f[9];
  const float* fb = feat + ((size_t)(b * NC) + t) * (HL * WL);
#pragma unroll
  for (int j = 0; j < 9; ++j) {
    int dy = j / 3 - 1, dx = (j % 3) - 1;
    int yy = y + dy, xx = x + dx;
    f[j] = (yy >= 0 && yy < HL && xx >= 0 && xx < WL) ? fb[yy * WL + xx] : 0.f;
  }
#pragma unroll 1
  for (int z = 0; z < NB; ++z) {
    float acc = 0.f;
#pragma unroll
    for (int j = 0; j < 9; ++j) acc += f[j] * wsm[z * 9 + j];
    gridh[(size_t)(((b * NB + z) * HL + y) * WL + x) * NC + t] = __float2half(acc * scale1024);
  }
  if (t < NB) {
    float s = 0.f;
#pragma unroll
    for (int j = 0; j < 9; ++j) s += wsm[t * 9 + j];
    den[(size_t)(b * NB + t) * (HL * WL) + p0] = s * scale;
  }
}

// ---------------- kernel D: slice, 2 px/thread, plain float2 stores -------
__global__ __launch_bounds__(512) void k_slice(const uint4* __restrict__ grid4,
                                               const float* __restrict__ den,
                                               const float* __restrict__ guide,
                                               float* __restrict__ out) {
  __shared__ uint4 glds[NCELL * LSTRIDE];   // 216*17*16 = 58752 B
  __shared__ float denL[NCELL];
  int bid = blockIdx.x;                 // 512 blocks: b(2) x th(32) x tw(8)
  int b = bid >> 8;
  int t = bid & 255;
  int th = t >> 3, tw = t & 7;
  int h0 = th * TH, w0 = tw * TW;
  int fy = (h0 * 31) / 511;
  int fx = (w0 * 31) / 511;
  int tid = threadIdx.x;

  // --- stage fp16 grid footprint: cellL = (ry*NRX+rx)*12 + z ---
#pragma unroll 1
  for (int i = tid; i < NCELL * 16; i += 512) {
    int cellL = i >> 4, q = i & 15;
    int rr = cellL / 12;
    int z = cellL - rr * 12;
    int ry = rr / NRX, rx = rr - ry * NRX;
    int gy = min(fy + ry, HL - 1);
    int gx = min(fx + rx, WL - 1);
    glds[cellL * LSTRIDE + (q ^ swzf(cellL))] =
        grid4[(size_t)(((b * NB + z) * HL + gy) * WL + gx) * 16 + q];
  }
  if (tid < NCELL) {
    int rr = tid / 12;
    int z = tid - rr * 12;
    int ry = rr / NRX, rx = rr - ry * NRX;
    int gy = min(fy + ry, HL - 1);
    int gx = min(fx + rx, WL - 1);
    denL[tid] = den[(size_t)(b * NB + z) * (HL * WL) + gy * WL + gx];
  }
  __syncthreads();

  // --- per-pixel params: thread owns 2 adjacent px ---
  const float SCC = 31.0f / 511.0f;
  int lh = tid >> 5;                 // 0..15
  int wp = (tid & 31) * 2;           // even w offset
  int h = h0 + lh;
  float wk_[2][8];
  int off_[2][8], sw_[2][8];
  const float* gb0 = guide + (size_t)b * 3 * PLANE + (size_t)h * WH + w0 + wp;
  float2 g0 = *(const float2*)(gb0);
  float2 g1 = *(const float2*)(gb0 + PLANE);
  float2 g2 = *(const float2*)(gb0 + 2 * PLANE);
#pragma unroll
  for (int p = 0; p < 2; ++p) {
    int w = w0 + wp + p;
    float luma = ((p ? g0.y : g0.x) + (p ? g1.y : g1.x) + (p ? g2.y : g2.x)) * (1.0f / 3.0f);
    float u = fminf((float)w * SCC, 31.0f);
    float v = fminf((float)h * SCC, 31.0f);
    float wz = fminf(fmaxf(luma * 11.0f, 0.0f), 11.0f);
    int x0 = (int)u; float fxw = u - (float)x0; int x1 = min(x0 + 1, WL - 1);
    int y0 = (int)v; float fyw = v - (float)y0; int y1 = min(y0 + 1, HL - 1);
    int z0 = (int)wz; float fzw = wz - (float)z0; int z1 = min(z0 + 1, NB - 1);
    int rx0 = x0 - fx, rx1 = min(x1 - fx, NRX - 1);
    int ry0 = y0 - fy, ry1 = min(y1 - fy, NRY - 1);
    int c00 = (ry0 * NRX + rx0) * 12, c01 = (ry0 * NRX + rx1) * 12;
    int c10 = (ry1 * NRX + rx0) * 12, c11 = (ry1 * NRX + rx1) * 12;
    float x0w = 1.f - fxw, x1w = fxw;
    float y0w = 1.f - fyw, y1w = fyw;
    float z0w = 1.f - fzw, z1w = fzw;
    int idx[8] = {c00 + z0, c01 + z0, c10 + z0, c11 + z0,
                  c00 + z1, c01 + z1, c10 + z1, c11 + z1};
    float wt[8];
    wt[0] = z0w * y0w * x0w; wt[1] = z0w * y0w * x1w;
    wt[2] = z0w * y1w * x0w; wt[3] = z0w * y1w * x1w;
    wt[4] = z1w * y0w * x0w; wt[5] = z1w * y0w * x1w;
    wt[6] = z1w * y1w * x0w; wt[7] = z1w * y1w * x1w;
    float dv = 0.f;
#pragma unroll
    for (int k = 0; k < 8; ++k) dv += wt[k] * denL[idx[k]];
    float rinv = 1.0f / (1024.0f * fmaxf(dv, 1e-8f));
#pragma unroll
    for (int k = 0; k < 8; ++k) {
      wk_[p][k] = wt[k] * rinv;
      off_[p][k] = idx[k] * LSTRIDE;
      sw_[p][k] = swzf(idx[k]);
    }
  }

  float* opb = out + ((size_t)(b * NC) << 18) + (size_t)h * WH + w0 + wp;
  // --- 16 channel-octets: 16 corner b128 reads (2 px), 8 f2 stores --------
#pragma unroll 2
  for (int cw = 0; cw < 16; ++cw) {
    float av[2][8];
#pragma unroll
    for (int p = 0; p < 2; ++p) {
#pragma unroll
      for (int c = 0; c < 8; ++c) av[p][c] = 0.f;
#pragma unroll
      for (int k = 0; k < 8; ++k) {
        uint4 q = glds[off_[p][k] + (cw ^ sw_[p][k])];
        const __half2* hp = (const __half2*)&q;
        float wkk = wk_[p][k];
        float2 f0 = __half22float2(hp[0]);
        float2 f1 = __half22float2(hp[1]);
        float2 f2 = __half22float2(hp[2]);
        float2 f3 = __half22float2(hp[3]);
        av[p][0] += wkk * f0.x; av[p][1] += wkk * f0.y;
        av[p][2] += wkk * f1.x; av[p][3] += wkk * f1.y;
        av[p][4] += wkk * f2.x; av[p][5] += wkk * f2.y;
        av[p][6] += wkk * f3.x; av[p][7] += wkk * f3.y;
      }
    }
    float* o0 = opb + ((size_t)(cw * 8) << 18);
#pragma unroll
    for (int c = 0; c < 8; ++c) {
      f2_t v2;
      v2.x = av[0][c];
      v2.y = av[1][c];
      *(f2_t*)(o0 + ((size_t)c << 18)) = v2;   // plain store: let L2 aggregate
    }
  }
}

extern "C" void kernel_launch(void* const* d_in, const int* in_sizes, int n_in,
                              void* d_out, int out_size, void* d_ws, size_t ws_size,
                              hipStream_t stream) {
  const float* feat   = (const float*)d_in[0];  // (2,128,32,32)
  const float* guide  = (const float*)d_in[1];  // (2,3,512,512)
  const float* sx_raw = (const float*)d_in[2];  // (1,1,32,32)
  const float* sy_raw = (const float*)d_in[3];  // (1,1,32,32)
  // d_in[4] = th_raw: unused by the output
  const float* sr_raw = (const float*)d_in[5];  // (1,1,32,32)
  float* out = (float*)d_out;

  char* ws = (char*)d_ws;
  float*  luma_lr = (float*)ws;                         // 8 KB
  float*  den     = (float*)(ws + 8192);                // 96 KB
  __half* gridh   = (__half*)(ws + 8192 + 98304);       // 6 MB (16B aligned)

  k_down<<<512, 256, 0, stream>>>(guide, luma_lr);
  k_grid<<<2048, 128, 0, stream>>>(feat, luma_lr, sx_raw, sy_raw, sr_raw, gridh, den);
  k_slice<<<512, 512, 0, stream>>>((const uint4*)gridh, den, guide, out);
}